// Round 7
// baseline (299.941 us; speedup 1.0000x reference)
//
#include <hip/hip_runtime.h>

typedef __bf16 bf16;
typedef __bf16 bf16x8 __attribute__((ext_vector_type(8)));
typedef __bf16 bf16x4 __attribute__((ext_vector_type(4)));
typedef float f32x4 __attribute__((ext_vector_type(4)));

__device__ __forceinline__ void gload_lds16(const void* g, void* l) {
  __builtin_amdgcn_global_load_lds(
      (const __attribute__((address_space(1))) void*)g,
      (__attribute__((address_space(3))) void*)l, 16, 0, 0);
}

__device__ __forceinline__ bf16x8 ld8(const bf16* p) {
  bf16x8 v; __builtin_memcpy(&v, p, 16); return v;
}

// ---------------- cast x (fp32 -> bf16), 8 elems/thread ----------------
__global__ __launch_bounds__(256) void cast_f32_bf16(const float* __restrict__ in,
                                                     bf16* __restrict__ out, int n8) {
  int i = blockIdx.x * 256 + threadIdx.x;
  if (i >= n8) return;
  const float4* p = (const float4*)in + (size_t)i * 2;
  float4 a = p[0], b = p[1];
  bf16x8 o;
  o[0] = (bf16)a.x; o[1] = (bf16)a.y; o[2] = (bf16)a.z; o[3] = (bf16)a.w;
  o[4] = (bf16)b.x; o[5] = (bf16)b.y; o[6] = (bf16)b.z; o[7] = (bf16)b.w;
  *((bf16x8*)out + i) = o;
}

// ---------------- transpose W (fp32 [K][N]) -> Wt (bf16 [N][K]) ----------------
__global__ __launch_bounds__(256) void transpose_w(const float* __restrict__ W,
                                                   bf16* __restrict__ Wt) {
  __shared__ bf16 tile[64][72];
  int t = threadIdx.x;
  int k0 = blockIdx.x * 64, n0 = blockIdx.y * 64;
  int r = t >> 2, c0 = (t & 3) * 16;
  const float* src = W + (size_t)(k0 + r) * 1536 + n0 + c0;
#pragma unroll
  for (int q = 0; q < 4; ++q) {
    float4 v = *(const float4*)(src + q * 4);
    tile[c0 + q * 4 + 0][r] = (bf16)v.x;
    tile[c0 + q * 4 + 1][r] = (bf16)v.y;
    tile[c0 + q * 4 + 2][r] = (bf16)v.z;
    tile[c0 + q * 4 + 3][r] = (bf16)v.w;
  }
  __syncthreads();
  bf16* dst = Wt + (size_t)(n0 + r) * 1536 + k0 + c0;
  bf16x8 o0, o1;
#pragma unroll
  for (int j = 0; j < 8; ++j) { o0[j] = tile[r][c0 + j]; o1[j] = tile[r][c0 + 8 + j]; }
  *(bf16x8*)dst = o0;
  *(bf16x8*)(dst + 8) = o1;
}

__global__ void concat_bias(const float* __restrict__ bq, const float* __restrict__ bk,
                            const float* __restrict__ bv, float* __restrict__ o) {
  int t = blockIdx.x * 256 + threadIdx.x;
  if (t < 1536) o[t] = bq[t];
  else if (t < 3072) o[t] = bk[t - 1536];
  else if (t < 4608) o[t] = bv[t - 3072];
}

// ---------------- m97-structure GEMM: C[M][N] = A[M][K](bf16) * B[N][K](bf16)^T + bias ----------------
template <typename OUT>
__global__ __launch_bounds__(256, 2) void gemm_bt(const bf16* __restrict__ A, const bf16* __restrict__ B,
                                                  const float* __restrict__ bias, OUT* __restrict__ C,
                                                  int M, int N, int K) {
  __shared__ bf16 As[128 * 32], Bs[128 * 32];
  int t = threadIdx.x, l = t & 63, w = t >> 6;
  int lane15 = l & 15, lhi = l >> 4;
  int m0 = blockIdx.x * 128, n0 = blockIdx.y * 128;
  int wm = (w >> 1) * 64, wn = (w & 1) * 64;
  f32x4 zero = {0.f, 0.f, 0.f, 0.f};
  f32x4 acc[4][4];
#pragma unroll
  for (int i = 0; i < 4; ++i)
#pragma unroll
    for (int j = 0; j < 4; ++j) acc[i][j] = zero;

  int srow = t >> 2, scol = (t & 3) * 8;
  const bf16* gA0 = A + (size_t)(m0 + srow) * K + scol;
  const bf16* gA1 = A + (size_t)(m0 + 64 + srow) * K + scol;
  const bf16* gB0 = B + (size_t)(n0 + srow) * K + scol;
  const bf16* gB1 = B + (size_t)(n0 + 64 + srow) * K + scol;
  char* ldsA = (char*)As + (size_t)w * 1024;
  char* ldsB = (char*)Bs + (size_t)w * 1024;

  for (int kt = 0; kt < K; kt += 32) {
    gload_lds16(gA0 + kt, ldsA);
    gload_lds16(gA1 + kt, ldsA + 4096);
    gload_lds16(gB0 + kt, ldsB);
    gload_lds16(gB1 + kt, ldsB + 4096);
    __syncthreads();
    bf16x8 af[4], bfr[4];
#pragma unroll
    for (int i = 0; i < 4; ++i) {
      af[i]  = ld8(&As[(wm + i * 16 + lane15) * 32 + lhi * 8]);
      bfr[i] = ld8(&Bs[(wn + i * 16 + lane15) * 32 + lhi * 8]);
    }
#pragma unroll
    for (int i = 0; i < 4; ++i)
#pragma unroll
      for (int j = 0; j < 4; ++j)
        acc[i][j] = __builtin_amdgcn_mfma_f32_16x16x32_bf16(af[i], bfr[j], acc[i][j], 0, 0, 0);
    __syncthreads();
  }
#pragma unroll
  for (int i = 0; i < 4; ++i)
#pragma unroll
    for (int j = 0; j < 4; ++j) {
      int col = n0 + wn + j * 16 + lane15;
      float bb = bias[col];
#pragma unroll
      for (int r = 0; r < 4; ++r) {
        int row = m0 + wm + i * 16 + lhi * 4 + r;
        C[(size_t)row * N + col] = (OUT)(acc[i][j][r] + bb);
      }
    }
}

// ---------------- RoPE cos/sin table [3584][64] ----------------
__global__ void rope_tab(const float* __restrict__ freqs, const int* __restrict__ gs,
                         float* __restrict__ tabc, float* __restrict__ tabs) {
  int idx = blockIdx.x * 256 + threadIdx.x;
  if (idx >= 3584 * 64) return;
  int s = idx >> 6, i = idx & 63;
  int H = gs[1], W = gs[2];
  int f = s / (H * W);
  int rem = s - f * (H * W);
  int hh = rem / W;
  int ww = rem - hh * W;
  int row = (i < 22) ? f : ((i < 43) ? hh : ww);
  float a = freqs[row * 64 + i];
  tabc[idx] = cosf(a);
  tabs[idx] = sinf(a);
}

// ---------------- RMSNorm + RoPE for Q,K; write head-major bf16 ----------------
__global__ __launch_bounds__(256) void postproc(const bf16* __restrict__ QKV,
    const float* __restrict__ gq, const float* __restrict__ gk,
    const float* __restrict__ tabc, const float* __restrict__ tabs,
    bf16* __restrict__ qb, bf16* __restrict__ kb) {
  int s = blockIdx.x, t = threadIdx.x;
  const bf16* Qr = QKV + (size_t)s * 4608;
  const bf16* Kr = Qr + 1536;
  int j0 = t * 6;
  float qv[6], kv[6];
  float sq = 0.f, sk = 0.f;
#pragma unroll
  for (int j = 0; j < 6; ++j) {
    float a = (float)Qr[j0 + j]; qv[j] = a; sq += a * a;
    float b = (float)Kr[j0 + j]; kv[j] = b; sk += b * b;
  }
#pragma unroll
  for (int off = 32; off > 0; off >>= 1) {
    sq += __shfl_down(sq, off);
    sk += __shfl_down(sk, off);
  }
  __shared__ float red[2][4];
  if ((t & 63) == 0) { red[0][t >> 6] = sq; red[1][t >> 6] = sk; }
  __syncthreads();
  float vq = (red[0][0] + red[0][1]) + (red[0][2] + red[0][3]);
  float vk = (red[1][0] + red[1][1]) + (red[1][2] + red[1][3]);
  float rq = 1.0f / sqrtf(vq * (1.0f / 1536.0f) + 1e-6f);
  float rk = 1.0f / sqrtf(vk * (1.0f / 1536.0f) + 1e-6f);
#pragma unroll
  for (int j = 0; j < 6; j += 2) {
    int jj = j0 + j;
    int d = jj & 127, i = d >> 1, h = jj >> 7;
    float c = tabc[s * 64 + i], sn = tabs[s * 64 + i];
    size_t base = (((size_t)h * 3584 + s) << 7) + d;
    float a = qv[j] * rq * gq[jj], b = qv[j + 1] * rq * gq[jj + 1];
    qb[base] = (bf16)(a * c - b * sn);
    qb[base + 1] = (bf16)(a * sn + b * c);
    float ak = kv[j] * rk * gk[jj], bk2 = kv[j + 1] * rk * gk[jj + 1];
    kb[base] = (bf16)(ak * c - bk2 * sn);
    kb[base + 1] = (bf16)(ak * sn + bk2 * c);
  }
}

// ---------------- V slice -> transposed bf16 vT [12][128][3584] ----------------
__global__ __launch_bounds__(256) void transpose_v(const bf16* __restrict__ QKV,
                                                   bf16* __restrict__ vT) {
  __shared__ bf16 tile[128][72];
  int t = threadIdx.x;
  int h = blockIdx.y;
  int s0 = blockIdx.x * 64;
  int r = t >> 2, c0 = (t & 3) * 32;
  const bf16* src = QKV + (size_t)(s0 + r) * 4608 + 3072 + h * 128 + c0;
#pragma unroll
  for (int q = 0; q < 4; ++q) {
    bf16x8 v = ld8(src + q * 8);
#pragma unroll
    for (int j = 0; j < 8; ++j) tile[c0 + q * 8 + j][r] = v[j];
  }
  __syncthreads();
  int d = t >> 1, sp = (t & 1) * 32;
  bf16* dst = vT + (size_t)(h * 128 + d) * 3584 + s0 + sp;
#pragma unroll
  for (int q = 0; q < 4; ++q) {
    bf16x8 o;
#pragma unroll
    for (int j = 0; j < 8; ++j) o[j] = tile[d][sp + q * 8 + j];
    *(bf16x8*)(dst + q * 8) = o;
  }
}

// ---------------- flash attention v3: single-buffer K/V, prefetch-after-barrier ----------------
// grid (28, 12, 2). Swapped mfma(K,Q): lane owns q = lane&15 (16 P values).
// kv slot relabeling makes lane's P values exactly its PV A-fragment.
// Pipeline: [bar; stage-writes; bar; prefetch-issue; compute]. The prefetch is
// issued AFTER the barrier so the compiler's vmcnt(0)-drain at the NEXT barrier
// waits on loads that are a full compute-phase old (free). R6 issued prefetch
// before the barrier -> every tile stalled the full load latency.
// Single-buffered K/V = 32 KB LDS -> up to 4 blocks/CU (was 2 at 64 KB).
// Softmax in exp2 domain (log2e folded into scale). T5 setprio around MFMA.
// launch_bounds min-waves MUST stay 2 (R4: (256,3) spilled the accumulators).
__global__ __launch_bounds__(256, 2) void flash_attn(
    const bf16* __restrict__ qb, const bf16* __restrict__ kb, const bf16* __restrict__ vT,
    const int* __restrict__ sl, float* __restrict__ po0, float* __restrict__ po1,
    float* __restrict__ ml) {
  const int L = 3584;
  __shared__ bf16 Ks[64 * 128];   // [kv][d], XOR-swizzled byte ^= ((kv&7)<<4)
  __shared__ bf16 Vs[128 * 64];   // [d][slot], XOR-swizzled byte ^= ((d&7)<<4)
  int t = threadIdx.x, l = t & 63;
  int lane15 = l & 15, lhi = l >> 4;
  int grp48 = l & 48;
  int h = blockIdx.y, z = blockIdx.z;
  int w = t >> 6;
  int qw = blockIdx.x * 128 + w * 32;
  int seqlen = sl[0];
  const float scale = 0.08838834764831845f * 1.44269504088896340f; // 1/sqrt(128) * log2(e)
  float* po = z ? po1 : po0;
  float* mlz = ml + (size_t)z * 12 * L * 2;

  bf16x8 aq[2][4];
#pragma unroll
  for (int qf = 0; qf < 2; ++qf)
#pragma unroll
    for (int kc = 0; kc < 4; ++kc)
      aq[qf][kc] = ld8(qb + (((size_t)h * L + qw + qf * 16 + lane15) << 7) + kc * 32 + lhi * 8);

  f32x4 zero = {0.f, 0.f, 0.f, 0.f};
  f32x4 out[2][8];
  float m2[2] = {-1e30f, -1e30f}, ls2[2] = {0.f, 0.f};
#pragma unroll
  for (int qf = 0; qf < 2; ++qf)
#pragma unroll
    for (int df = 0; df < 8; ++df) out[qf][df] = zero;

  int nt = (seqlen + 63) >> 6;
  if (nt > 56) nt = 56;
  int t0 = z * 28, t1 = t0 + 28;
  if (t1 > nt) t1 = nt;

  // staging coordinates (constant per thread)
  int rk_s = t >> 4, ck_s = (t & 15) * 16;         // K: row-sub, byte col (256B row)
  int rv_s = t >> 3;                               // V: d-row-sub
  int mm = t & 7;                                  // V: which 8-kv chunk
  int sA = 32 * (mm >> 2) + 16 * (mm & 1) + 4 * ((mm >> 1) & 1);  // slot of kv 8*mm
  int oA = 2 * sA;                                 // byte col of first 4 slots
  int swzk = (rk_s & 7) << 4;
  int swzv = (rv_s & 7) << 4;

  bf16x8 kreg[4], vreg[4];
  if (t0 < t1) {
    int kv0 = t0 * 64;
#pragma unroll
    for (int p = 0; p < 4; ++p) {
      kreg[p] = ld8(kb + (((size_t)h * L + kv0 + p * 16 + rk_s) << 7) + (ck_s >> 1));
      vreg[p] = ld8(vT + (size_t)(h * 128 + p * 32 + rv_s) * L + kv0 + mm * 8);
    }
  }

  for (int ti = t0; ti < t1; ++ti) {
    int kv0 = ti * 64;
    __syncthreads();   // WAR: all waves done reading prev tile (drain is stale -> free)
    // ---- stage writes (consume prefetched regs; K rows; V at slot-permuted cols) ----
#pragma unroll
    for (int p = 0; p < 4; ++p) {
      __builtin_memcpy((char*)Ks + (p * 16 + rk_s) * 256 + (ck_s ^ swzk), &kreg[p], 16);
      bf16x4 lo, hi;
#pragma unroll
      for (int j = 0; j < 4; ++j) { lo[j] = vreg[p][j]; hi[j] = vreg[p][j + 4]; }
      char* vrow = (char*)Vs + (p * 32 + rv_s) * 128;
      __builtin_memcpy(vrow + (oA ^ swzv), &lo, 8);
      __builtin_memcpy(vrow + ((oA + 16) ^ swzv), &hi, 8);
    }
    __syncthreads();   // RAW: writes visible (no recent vmem -> free)
    // ---- prefetch next tile now; a full compute phase hides the latency ----
    if (ti + 1 < t1) {
      int kn = (ti + 1) * 64;
#pragma unroll
      for (int p = 0; p < 4; ++p) {
        kreg[p] = ld8(kb + (((size_t)h * L + kn + p * 16 + rk_s) << 7) + (ck_s >> 1));
        vreg[p] = ld8(vT + (size_t)(h * 128 + p * 32 + rv_s) * L + kn + mm * 8);
      }
    }

    // ---- S^T = mfma(K, Q): lane owns q = lane15; kv = 16a + 4*lhi + r ----
    f32x4 sc[2][4];
#pragma unroll
    for (int qf = 0; qf < 2; ++qf)
#pragma unroll
      for (int a = 0; a < 4; ++a) sc[qf][a] = zero;
    __builtin_amdgcn_s_setprio(1);
#pragma unroll
    for (int a = 0; a < 4; ++a) {
      int rk = a * 16 + lane15;
      const char* krow = (const char*)Ks + rk * 256;
      int swz = (rk & 7) << 4;
#pragma unroll
      for (int kc = 0; kc < 4; ++kc) {
        bf16x8 bk_ = ld8((const bf16*)(krow + ((kc * 64 + lhi * 16) ^ swz)));
        sc[0][a] = __builtin_amdgcn_mfma_f32_16x16x32_bf16(bk_, aq[0][kc], sc[0][a], 0, 0, 0);
        sc[1][a] = __builtin_amdgcn_mfma_f32_16x16x32_bf16(bk_, aq[1][kc], sc[1][a], 0, 0, 0);
      }
    }
    __builtin_amdgcn_s_setprio(0);

    // ---- in-register online softmax, exp2 domain ----
    bool full = (kv0 + 64 <= seqlen);
    bf16x8 ap[2][2];
#pragma unroll
    for (int qf = 0; qf < 2; ++qf) {
      float tm = -1e30f;
#pragma unroll
      for (int a = 0; a < 4; ++a)
#pragma unroll
        for (int r = 0; r < 4; ++r) {
          float s = sc[qf][a][r] * scale;
          if (!full) {
            int col = kv0 + a * 16 + lhi * 4 + r;
            s = (col < seqlen) ? s : -1e30f;
          }
          sc[qf][a][r] = s;
          tm = fmaxf(tm, s);
        }
      tm = fmaxf(tm, __shfl_xor(tm, 16));
      tm = fmaxf(tm, __shfl_xor(tm, 32));
      if (!__all(tm <= m2[qf] + 11.54f)) {  // defer-max (8 nats = 11.54 bits)
        float nm = fmaxf(m2[qf], tm);
        float f = exp2f(m2[qf] - nm);
        m2[qf] = nm;
        ls2[qf] *= f;
#pragma unroll
        for (int r = 0; r < 4; ++r) {
          float fr = __shfl(f, grp48 | (lhi * 4 + r));   // stats live at lane&15 == q
#pragma unroll
          for (int df = 0; df < 8; ++df) out[qf][df][r] *= fr;
        }
      }
      float psum = 0.f;
#pragma unroll
      for (int a = 0; a < 4; ++a)
#pragma unroll
        for (int r = 0; r < 4; ++r) {
          float p = exp2f(sc[qf][a][r] - m2[qf]);
          sc[qf][a][r] = p;
          psum += p;
        }
      psum += __shfl_xor(psum, 16);
      psum += __shfl_xor(psum, 32);
      ls2[qf] += psum;
      // PV A-fragments: own values in slot order [p[2c][0..3], p[2c+1][0..3]]
#pragma unroll
      for (int c = 0; c < 2; ++c) {
        bf16x8 f8;
#pragma unroll
        for (int r = 0; r < 4; ++r) {
          f8[r] = (bf16)sc[qf][2 * c][r];
          f8[r + 4] = (bf16)sc[qf][2 * c + 1][r];
        }
        ap[qf][c] = f8;
      }
    }

    // ---- O += P V (V read at matching slots) ----
    __builtin_amdgcn_s_setprio(1);
#pragma unroll
    for (int df = 0; df < 8; ++df) {
      int rd = df * 16 + lane15;
      const char* vrow2 = (const char*)Vs + rd * 128;
      int swz = (rd & 7) << 4;
#pragma unroll
      for (int c = 0; c < 2; ++c) {
        bf16x8 bv_ = ld8((const bf16*)(vrow2 + ((c * 64 + lhi * 16) ^ swz)));
        out[0][df] = __builtin_amdgcn_mfma_f32_16x16x32_bf16(ap[0][c], bv_, out[0][df], 0, 0, 0);
        out[1][df] = __builtin_amdgcn_mfma_f32_16x16x32_bf16(ap[1][c], bv_, out[1][df], 0, 0, 0);
      }
    }
    __builtin_amdgcn_s_setprio(0);
  }

  // ---- write unnormalized partials + (m, l) ----
#pragma unroll
  for (int qf = 0; qf < 2; ++qf) {
#pragma unroll
    for (int r = 0; r < 4; ++r) {
      int row = qw + qf * 16 + lhi * 4 + r;
      size_t rbase = ((size_t)h * L + row) << 7;
#pragma unroll
      for (int df = 0; df < 8; ++df)
        po[rbase + df * 16 + lane15] = out[qf][df][r];
    }
    if (lhi == 0) {
      int row = qw + qf * 16 + lane15;
      mlz[(((size_t)h * L + row) << 1)] = m2[qf];
      mlz[(((size_t)h * L + row) << 1) + 1] = ls2[qf];
    }
  }
}

// ---------------- combine the two KV-split halves (m,l are in exp2 domain) ----------------
__global__ __launch_bounds__(256) void combine_halves(
    const float* __restrict__ po0, const float* __restrict__ po1,
    const float* __restrict__ ml, bf16* __restrict__ attn) {
  const int L = 3584;
  int row = blockIdx.x * 8 + (threadIdx.x >> 5);   // h*L + s
  int c0 = (threadIdx.x & 31) * 4;
  const float* ml0 = ml;
  const float* ml1 = ml + (size_t)12 * L * 2;
  float m0 = ml0[row * 2], l0 = ml0[row * 2 + 1];
  float m1 = ml1[row * 2], l1 = ml1[row * 2 + 1];
  float M = fmaxf(m0, m1);
  float w0 = exp2f(m0 - M), w1 = exp2f(m1 - M);
  float inv = 1.0f / fmaxf(w0 * l0 + w1 * l1, 1e-30f);
  float4 a = *(const float4*)(po0 + (size_t)row * 128 + c0);
  float4 b = *(const float4*)(po1 + (size_t)row * 128 + c0);
  int h = row / L, s = row % L;
  bf16x4 o;
  o[0] = (bf16)((w0 * a.x + w1 * b.x) * inv);
  o[1] = (bf16)((w0 * a.y + w1 * b.y) * inv);
  o[2] = (bf16)((w0 * a.z + w1 * b.z) * inv);
  o[3] = (bf16)((w0 * a.w + w1 * b.w) * inv);
  *(bf16x4*)(attn + (size_t)s * 1536 + h * 128 + c0) = o;
}

// ---------------- launcher ----------------
extern "C" void kernel_launch(void* const* d_in, const int* in_sizes, int n_in,
                              void* d_out, int out_size, void* d_ws, size_t ws_size,
                              hipStream_t stream) {
  const float* x = (const float*)d_in[0];
  const int* seq_lens = (const int*)d_in[1];
  const int* grid_sizes = (const int*)d_in[2];
  const float* freqs = (const float*)d_in[3];
  const float* Wq = (const float*)d_in[4];
  const float* bq = (const float*)d_in[5];
  const float* Wk = (const float*)d_in[6];
  const float* bk = (const float*)d_in[7];
  const float* Wv = (const float*)d_in[8];
  const float* bv = (const float*)d_in[9];
  const float* Wo = (const float*)d_in[10];
  const float* bo = (const float*)d_in[11];
  const float* gq = (const float*)d_in[12];
  const float* gk = (const float*)d_in[13];

  char* ws = (char*)d_ws;
  bf16* x_bf = (bf16*)(ws + 0);             // 11,010,048  (dead after QKV GEMM)
  bf16* wqkvt = (bf16*)(ws + 11010048);     // 14,155,776  (dead after QKV GEMM)
  bf16* wot = (bf16*)(ws + 25165824);       //  4,718,592  (live until final GEMM)
  float* bqkv = (float*)(ws + 29884416);    //     18,432
  bf16* QKV = (bf16*)(ws + 29902848);       // 33,030,144  (dead after transpose_v)
  bf16* qb = (bf16*)(ws + 62932992);        // 11,010,048
  bf16* kb = (bf16*)(ws + 73943040);        // 11,010,048
  bf16* vT = (bf16*)(ws + 84953088);        // 11,010,048
  float* tabc = (float*)(ws + 95963136);    //    917,504  (dead after postproc)
  float* tabs = (float*)(ws + 96880640);    //    917,504  (dead after postproc)
  // overlays for the flash phase (underlying buffers dead by then)
  float* po0 = (float*)(ws + 29902848);     // 22,020,096 over QKV
  bf16* attn = (bf16*)(ws + 51922944);      // 11,010,048 over QKV tail
  float* po1 = (float*)(ws + 0);            // 22,020,096 over x_bf+wqkvt
  float* ml  = (float*)(ws + 95963136);     //    688,128 over tabc+tabs

  cast_f32_bf16<<<2688, 256, 0, stream>>>(x, x_bf, 688128);
  transpose_w<<<dim3(24, 24), 256, 0, stream>>>(Wq, wqkvt);
  transpose_w<<<dim3(24, 24), 256, 0, stream>>>(Wk, wqkvt + 1536 * 1536);
  transpose_w<<<dim3(24, 24), 256, 0, stream>>>(Wv, wqkvt + 2 * 1536 * 1536);
  transpose_w<<<dim3(24, 24), 256, 0, stream>>>(Wo, wot);
  concat_bias<<<18, 256, 0, stream>>>(bq, bk, bv, bqkv);
  rope_tab<<<896, 256, 0, stream>>>(freqs, grid_sizes, tabc, tabs);
  gemm_bt<bf16><<<dim3(28, 36), 256, 0, stream>>>(x_bf, wqkvt, bqkv, QKV, 3584, 4608, 1536);
  postproc<<<3584, 256, 0, stream>>>(QKV, gq, gk, tabc, tabs, qb, kb);
  transpose_v<<<dim3(56, 12), 256, 0, stream>>>(QKV, vT);
  flash_attn<<<dim3(28, 12, 2), 256, 0, stream>>>(qb, kb, vT, seq_lens, po0, po1, ml);
  combine_halves<<<5376, 256, 0, stream>>>(po0, po1, ml, attn);
  gemm_bt<float><<<dim3(28, 12), 256, 0, stream>>>(attn, wot, bo, (float*)d_out, 3584, 1536, 1536);
}

// Round 8
// 281.477 us; speedup vs baseline: 1.0656x; 1.0656x over previous
//
#include <hip/hip_runtime.h>

typedef __bf16 bf16;
typedef __bf16 bf16x8 __attribute__((ext_vector_type(8)));
typedef __bf16 bf16x4 __attribute__((ext_vector_type(4)));
typedef float f32x4 __attribute__((ext_vector_type(4)));

__device__ __forceinline__ void gload_lds16(const void* g, void* l) {
  __builtin_amdgcn_global_load_lds(
      (const __attribute__((address_space(1))) void*)g,
      (__attribute__((address_space(3))) void*)l, 16, 0, 0);
}

__device__ __forceinline__ bf16x8 ld8(const bf16* p) {
  bf16x8 v; __builtin_memcpy(&v, p, 16); return v;
}

// ---------------- cast x (fp32 -> bf16), 8 elems/thread ----------------
__global__ __launch_bounds__(256) void cast_f32_bf16(const float* __restrict__ in,
                                                     bf16* __restrict__ out, int n8) {
  int i = blockIdx.x * 256 + threadIdx.x;
  if (i >= n8) return;
  const float4* p = (const float4*)in + (size_t)i * 2;
  float4 a = p[0], b = p[1];
  bf16x8 o;
  o[0] = (bf16)a.x; o[1] = (bf16)a.y; o[2] = (bf16)a.z; o[3] = (bf16)a.w;
  o[4] = (bf16)b.x; o[5] = (bf16)b.y; o[6] = (bf16)b.z; o[7] = (bf16)b.w;
  *((bf16x8*)out + i) = o;
}

// ---------------- transpose W (fp32 [K][N]) -> Wt (bf16 [N][K]) ----------------
__global__ __launch_bounds__(256) void transpose_w(const float* __restrict__ W,
                                                   bf16* __restrict__ Wt) {
  __shared__ bf16 tile[64][72];
  int t = threadIdx.x;
  int k0 = blockIdx.x * 64, n0 = blockIdx.y * 64;
  int r = t >> 2, c0 = (t & 3) * 16;
  const float* src = W + (size_t)(k0 + r) * 1536 + n0 + c0;
#pragma unroll
  for (int q = 0; q < 4; ++q) {
    float4 v = *(const float4*)(src + q * 4);
    tile[c0 + q * 4 + 0][r] = (bf16)v.x;
    tile[c0 + q * 4 + 1][r] = (bf16)v.y;
    tile[c0 + q * 4 + 2][r] = (bf16)v.z;
    tile[c0 + q * 4 + 3][r] = (bf16)v.w;
  }
  __syncthreads();
  bf16* dst = Wt + (size_t)(n0 + r) * 1536 + k0 + c0;
  bf16x8 o0, o1;
#pragma unroll
  for (int j = 0; j < 8; ++j) { o0[j] = tile[r][c0 + j]; o1[j] = tile[r][c0 + 8 + j]; }
  *(bf16x8*)dst = o0;
  *(bf16x8*)(dst + 8) = o1;
}

__global__ void concat_bias(const float* __restrict__ bq, const float* __restrict__ bk,
                            const float* __restrict__ bv, float* __restrict__ o) {
  int t = blockIdx.x * 256 + threadIdx.x;
  if (t < 1536) o[t] = bq[t];
  else if (t < 3072) o[t] = bk[t - 1536];
  else if (t < 4608) o[t] = bv[t - 3072];
}

// ---------------- m97-structure GEMM: C[M][N] = A[M][K](bf16) * B[N][K](bf16)^T + bias ----------------
template <typename OUT>
__global__ __launch_bounds__(256, 2) void gemm_bt(const bf16* __restrict__ A, const bf16* __restrict__ B,
                                                  const float* __restrict__ bias, OUT* __restrict__ C,
                                                  int M, int N, int K) {
  __shared__ bf16 As[128 * 32], Bs[128 * 32];
  int t = threadIdx.x, l = t & 63, w = t >> 6;
  int lane15 = l & 15, lhi = l >> 4;
  int m0 = blockIdx.x * 128, n0 = blockIdx.y * 128;
  int wm = (w >> 1) * 64, wn = (w & 1) * 64;
  f32x4 zero = {0.f, 0.f, 0.f, 0.f};
  f32x4 acc[4][4];
#pragma unroll
  for (int i = 0; i < 4; ++i)
#pragma unroll
    for (int j = 0; j < 4; ++j) acc[i][j] = zero;

  int srow = t >> 2, scol = (t & 3) * 8;
  const bf16* gA0 = A + (size_t)(m0 + srow) * K + scol;
  const bf16* gA1 = A + (size_t)(m0 + 64 + srow) * K + scol;
  const bf16* gB0 = B + (size_t)(n0 + srow) * K + scol;
  const bf16* gB1 = B + (size_t)(n0 + 64 + srow) * K + scol;
  char* ldsA = (char*)As + (size_t)w * 1024;
  char* ldsB = (char*)Bs + (size_t)w * 1024;

  for (int kt = 0; kt < K; kt += 32) {
    gload_lds16(gA0 + kt, ldsA);
    gload_lds16(gA1 + kt, ldsA + 4096);
    gload_lds16(gB0 + kt, ldsB);
    gload_lds16(gB1 + kt, ldsB + 4096);
    __syncthreads();
    bf16x8 af[4], bfr[4];
#pragma unroll
    for (int i = 0; i < 4; ++i) {
      af[i]  = ld8(&As[(wm + i * 16 + lane15) * 32 + lhi * 8]);
      bfr[i] = ld8(&Bs[(wn + i * 16 + lane15) * 32 + lhi * 8]);
    }
#pragma unroll
    for (int i = 0; i < 4; ++i)
#pragma unroll
      for (int j = 0; j < 4; ++j)
        acc[i][j] = __builtin_amdgcn_mfma_f32_16x16x32_bf16(af[i], bfr[j], acc[i][j], 0, 0, 0);
    __syncthreads();
  }
#pragma unroll
  for (int i = 0; i < 4; ++i)
#pragma unroll
    for (int j = 0; j < 4; ++j) {
      int col = n0 + wn + j * 16 + lane15;
      float bb = bias[col];
#pragma unroll
      for (int r = 0; r < 4; ++r) {
        int row = m0 + wm + i * 16 + lhi * 4 + r;
        C[(size_t)row * N + col] = (OUT)(acc[i][j][r] + bb);
      }
    }
}

// ---------------- RoPE cos/sin table [3584][64] ----------------
__global__ void rope_tab(const float* __restrict__ freqs, const int* __restrict__ gs,
                         float* __restrict__ tabc, float* __restrict__ tabs) {
  int idx = blockIdx.x * 256 + threadIdx.x;
  if (idx >= 3584 * 64) return;
  int s = idx >> 6, i = idx & 63;
  int H = gs[1], W = gs[2];
  int f = s / (H * W);
  int rem = s - f * (H * W);
  int hh = rem / W;
  int ww = rem - hh * W;
  int row = (i < 22) ? f : ((i < 43) ? hh : ww);
  float a = freqs[row * 64 + i];
  tabc[idx] = cosf(a);
  tabs[idx] = sinf(a);
}

// ---------------- RMSNorm + RoPE for Q,K; write head-major bf16 ----------------
__global__ __launch_bounds__(256) void postproc(const bf16* __restrict__ QKV,
    const float* __restrict__ gq, const float* __restrict__ gk,
    const float* __restrict__ tabc, const float* __restrict__ tabs,
    bf16* __restrict__ qb, bf16* __restrict__ kb) {
  int s = blockIdx.x, t = threadIdx.x;
  const bf16* Qr = QKV + (size_t)s * 4608;
  const bf16* Kr = Qr + 1536;
  int j0 = t * 6;
  float qv[6], kv[6];
  float sq = 0.f, sk = 0.f;
#pragma unroll
  for (int j = 0; j < 6; ++j) {
    float a = (float)Qr[j0 + j]; qv[j] = a; sq += a * a;
    float b = (float)Kr[j0 + j]; kv[j] = b; sk += b * b;
  }
#pragma unroll
  for (int off = 32; off > 0; off >>= 1) {
    sq += __shfl_down(sq, off);
    sk += __shfl_down(sk, off);
  }
  __shared__ float red[2][4];
  if ((t & 63) == 0) { red[0][t >> 6] = sq; red[1][t >> 6] = sk; }
  __syncthreads();
  float vq = (red[0][0] + red[0][1]) + (red[0][2] + red[0][3]);
  float vk = (red[1][0] + red[1][1]) + (red[1][2] + red[1][3]);
  float rq = 1.0f / sqrtf(vq * (1.0f / 1536.0f) + 1e-6f);
  float rk = 1.0f / sqrtf(vk * (1.0f / 1536.0f) + 1e-6f);
#pragma unroll
  for (int j = 0; j < 6; j += 2) {
    int jj = j0 + j;
    int d = jj & 127, i = d >> 1, h = jj >> 7;
    float c = tabc[s * 64 + i], sn = tabs[s * 64 + i];
    size_t base = (((size_t)h * 3584 + s) << 7) + d;
    float a = qv[j] * rq * gq[jj], b = qv[j + 1] * rq * gq[jj + 1];
    qb[base] = (bf16)(a * c - b * sn);
    qb[base + 1] = (bf16)(a * sn + b * c);
    float ak = kv[j] * rk * gk[jj], bk2 = kv[j + 1] * rk * gk[jj + 1];
    kb[base] = (bf16)(ak * c - bk2 * sn);
    kb[base + 1] = (bf16)(ak * sn + bk2 * c);
  }
}

// ---------------- V slice -> transposed bf16 vT [12][128][3584] ----------------
__global__ __launch_bounds__(256) void transpose_v(const bf16* __restrict__ QKV,
                                                   bf16* __restrict__ vT) {
  __shared__ bf16 tile[128][72];
  int t = threadIdx.x;
  int h = blockIdx.y;
  int s0 = blockIdx.x * 64;
  int r = t >> 2, c0 = (t & 3) * 32;
  const bf16* src = QKV + (size_t)(s0 + r) * 4608 + 3072 + h * 128 + c0;
#pragma unroll
  for (int q = 0; q < 4; ++q) {
    bf16x8 v = ld8(src + q * 8);
#pragma unroll
    for (int j = 0; j < 8; ++j) tile[c0 + q * 8 + j][r] = v[j];
  }
  __syncthreads();
  int d = t >> 1, sp = (t & 1) * 32;
  bf16* dst = vT + (size_t)(h * 128 + d) * 3584 + s0 + sp;
#pragma unroll
  for (int q = 0; q < 4; ++q) {
    bf16x8 o;
#pragma unroll
    for (int j = 0; j < 8; ++j) o[j] = tile[d][sp + q * 8 + j];
    *(bf16x8*)(dst + q * 8) = o;
  }
}

// ---------------- flash attention v2-core (R6 verbatim), KV-split 4 ----------------
// grid (28, 12, 4). Swapped mfma(K,Q): lane owns q = lane&15 (16 P values);
// kv slot relabeling makes lane's own P values exactly its PV A-fragment.
// Double-buffered K/V, ONE barrier per tile (waves may drift ~a tile apart —
// R7 showed this inter-wave slack beats single-buffer lockstep). Prefetch
// issued before the barrier (R6-verified). Defer-max THR=8. No setprio.
// launch_bounds min-waves MUST stay 2 (R4: (256,3) spilled the accumulators).
__global__ __launch_bounds__(256, 2) void flash_attn(
    const bf16* __restrict__ qb, const bf16* __restrict__ kb, const bf16* __restrict__ vT,
    const int* __restrict__ sl, float* __restrict__ po0, float* __restrict__ po1,
    float* __restrict__ po2, float* __restrict__ po3, float* __restrict__ ml) {
  const int L = 3584;
  __shared__ bf16 Ks[2][64 * 128];   // [kv][d], XOR-swizzled byte ^= ((kv&7)<<4)
  __shared__ bf16 Vs[2][128 * 64];   // [d][slot], XOR-swizzled byte ^= ((d&7)<<4)
  int t = threadIdx.x, l = t & 63, w = t >> 6;
  int lane15 = l & 15, lhi = l >> 4;
  int grp48 = l & 48;
  int h = blockIdx.y, z = blockIdx.z;
  int qw = blockIdx.x * 128 + w * 32;
  int seqlen = sl[0];
  const float scale = 0.08838834764831845f; // 1/sqrt(128)
  float* po = (z == 0) ? po0 : (z == 1) ? po1 : (z == 2) ? po2 : po3;
  float* mlz = ml + (size_t)z * 12 * L * 2;

  bf16x8 aq[2][4];
#pragma unroll
  for (int qf = 0; qf < 2; ++qf)
#pragma unroll
    for (int kc = 0; kc < 4; ++kc)
      aq[qf][kc] = ld8(qb + (((size_t)h * L + qw + qf * 16 + lane15) << 7) + kc * 32 + lhi * 8);

  f32x4 zero = {0.f, 0.f, 0.f, 0.f};
  f32x4 out[2][8];
  float m2[2] = {-1e30f, -1e30f}, ls2[2] = {0.f, 0.f};
#pragma unroll
  for (int qf = 0; qf < 2; ++qf)
#pragma unroll
    for (int df = 0; df < 8; ++df) out[qf][df] = zero;

  int nt = (seqlen + 63) >> 6;
  if (nt > 56) nt = 56;
  int t0 = z * 14, t1 = t0 + 14;
  if (t0 > nt) t0 = nt;
  if (t1 > nt) t1 = nt;

  // staging coordinates (constant per thread)
  int rk_s = t >> 4, ck_s = (t & 15) * 16;         // K: row-sub, byte col (256B row)
  int rv_s = t >> 3;                               // V: d-row-sub
  int mm = t & 7;                                  // V: which 8-kv chunk
  int sA = 32 * (mm >> 2) + 16 * (mm & 1) + 4 * ((mm >> 1) & 1);  // slot of kv 8*mm
  int oA = 2 * sA;                                 // byte col of first 4 slots
  int swzk = (rk_s & 7) << 4;
  int swzv = (rv_s & 7) << 4;

  bf16x8 kreg[4], vreg[4];
  if (t0 < t1) {
    int kv0 = t0 * 64;
#pragma unroll
    for (int p = 0; p < 4; ++p) {
      kreg[p] = ld8(kb + (((size_t)h * L + kv0 + p * 16 + rk_s) << 7) + (ck_s >> 1));
      vreg[p] = ld8(vT + (size_t)(h * 128 + p * 32 + rv_s) * L + kv0 + mm * 8);
    }
  }

  int buf = 0;
  for (int ti = t0; ti < t1; ++ti) {
    int kv0 = ti * 64;
    // ---- write staged regs into LDS buf (K rows; V at slot-permuted cols) ----
#pragma unroll
    for (int p = 0; p < 4; ++p) {
      __builtin_memcpy((char*)Ks[buf] + (p * 16 + rk_s) * 256 + (ck_s ^ swzk), &kreg[p], 16);
      bf16x4 lo, hi;
#pragma unroll
      for (int j = 0; j < 4; ++j) { lo[j] = vreg[p][j]; hi[j] = vreg[p][j + 4]; }
      char* vrow = (char*)Vs[buf] + (p * 32 + rv_s) * 128;
      __builtin_memcpy(vrow + (oA ^ swzv), &lo, 8);
      __builtin_memcpy(vrow + ((oA + 16) ^ swzv), &hi, 8);
    }
    // issue next tile's global loads (full tile of compute hides them)
    if (ti + 1 < t1) {
      int kn = (ti + 1) * 64;
#pragma unroll
      for (int p = 0; p < 4; ++p) {
        kreg[p] = ld8(kb + (((size_t)h * L + kn + p * 16 + rk_s) << 7) + (ck_s >> 1));
        vreg[p] = ld8(vT + (size_t)(h * 128 + p * 32 + rv_s) * L + kn + mm * 8);
      }
    }
    __syncthreads();

    // ---- S^T = mfma(K, Q): lane owns q = lane15; kv = 16a + 4*lhi + r ----
    f32x4 sc[2][4];
#pragma unroll
    for (int qf = 0; qf < 2; ++qf)
#pragma unroll
      for (int a = 0; a < 4; ++a) sc[qf][a] = zero;
#pragma unroll
    for (int a = 0; a < 4; ++a) {
      int rk = a * 16 + lane15;
      const char* krow = (const char*)Ks[buf] + rk * 256;
      int swz = (rk & 7) << 4;
#pragma unroll
      for (int kc = 0; kc < 4; ++kc) {
        bf16x8 bk_ = ld8((const bf16*)(krow + ((kc * 64 + lhi * 16) ^ swz)));
        sc[0][a] = __builtin_amdgcn_mfma_f32_16x16x32_bf16(bk_, aq[0][kc], sc[0][a], 0, 0, 0);
        sc[1][a] = __builtin_amdgcn_mfma_f32_16x16x32_bf16(bk_, aq[1][kc], sc[1][a], 0, 0, 0);
      }
    }

    // ---- in-register online softmax (per qf; lane holds full row slice) ----
    bool full = (kv0 + 64 <= seqlen);
    bf16x8 ap[2][2];
#pragma unroll
    for (int qf = 0; qf < 2; ++qf) {
      float tm = -1e30f;
#pragma unroll
      for (int a = 0; a < 4; ++a)
#pragma unroll
        for (int r = 0; r < 4; ++r) {
          float s = sc[qf][a][r] * scale;
          if (!full) {
            int col = kv0 + a * 16 + lhi * 4 + r;
            s = (col < seqlen) ? s : -1e30f;
          }
          sc[qf][a][r] = s;
          tm = fmaxf(tm, s);
        }
      tm = fmaxf(tm, __shfl_xor(tm, 16));
      tm = fmaxf(tm, __shfl_xor(tm, 32));
      if (!__all(tm <= m2[qf] + 8.0f)) {   // defer-max: rescale only on real growth
        float nm = fmaxf(m2[qf], tm);
        float f = __expf(m2[qf] - nm);
        m2[qf] = nm;
        ls2[qf] *= f;
#pragma unroll
        for (int r = 0; r < 4; ++r) {
          float fr = __shfl(f, grp48 | (lhi * 4 + r));   // stats live at lane&15 == q
#pragma unroll
          for (int df = 0; df < 8; ++df) out[qf][df][r] *= fr;
        }
      }
      float psum = 0.f;
#pragma unroll
      for (int a = 0; a < 4; ++a)
#pragma unroll
        for (int r = 0; r < 4; ++r) {
          float p = __expf(sc[qf][a][r] - m2[qf]);
          sc[qf][a][r] = p;
          psum += p;
        }
      psum += __shfl_xor(psum, 16);
      psum += __shfl_xor(psum, 32);
      ls2[qf] += psum;
      // PV A-fragments: own values in slot order [p[2c][0..3], p[2c+1][0..3]]
#pragma unroll
      for (int c = 0; c < 2; ++c) {
        bf16x8 f8;
#pragma unroll
        for (int r = 0; r < 4; ++r) {
          f8[r] = (bf16)sc[qf][2 * c][r];
          f8[r + 4] = (bf16)sc[qf][2 * c + 1][r];
        }
        ap[qf][c] = f8;
      }
    }

    // ---- O += P V (V read at matching slots) ----
#pragma unroll
    for (int df = 0; df < 8; ++df) {
      int rd = df * 16 + lane15;
      const char* vrow2 = (const char*)Vs[buf] + rd * 128;
      int swz = (rd & 7) << 4;
#pragma unroll
      for (int c = 0; c < 2; ++c) {
        bf16x8 bv_ = ld8((const bf16*)(vrow2 + ((c * 64 + lhi * 16) ^ swz)));
        out[0][df] = __builtin_amdgcn_mfma_f32_16x16x32_bf16(ap[0][c], bv_, out[0][df], 0, 0, 0);
        out[1][df] = __builtin_amdgcn_mfma_f32_16x16x32_bf16(ap[1][c], bv_, out[1][df], 0, 0, 0);
      }
    }
    buf ^= 1;
  }

  // ---- write unnormalized partials + (m, l) ----
#pragma unroll
  for (int qf = 0; qf < 2; ++qf) {
#pragma unroll
    for (int r = 0; r < 4; ++r) {
      int row = qw + qf * 16 + lhi * 4 + r;
      size_t rbase = ((size_t)h * L + row) << 7;
#pragma unroll
      for (int df = 0; df < 8; ++df)
        po[rbase + df * 16 + lane15] = out[qf][df][r];
    }
    if (lhi == 0) {
      int row = qw + qf * 16 + lane15;
      mlz[(((size_t)h * L + row) << 1)] = m2[qf];
      mlz[(((size_t)h * L + row) << 1) + 1] = ls2[qf];
    }
  }
}

// ---------------- combine the four KV-split slices ----------------
__global__ __launch_bounds__(256) void combine4(
    const float* __restrict__ po0, const float* __restrict__ po1,
    const float* __restrict__ po2, const float* __restrict__ po3,
    const float* __restrict__ ml, bf16* __restrict__ attn) {
  const int L = 3584;
  int row = blockIdx.x * 8 + (threadIdx.x >> 5);   // h*L + s
  int c0 = (threadIdx.x & 31) * 4;
  const size_t mls = (size_t)12 * L * 2;
  float m0 = ml[row * 2],           l0 = ml[row * 2 + 1];
  float m1 = ml[mls + row * 2],     l1 = ml[mls + row * 2 + 1];
  float m2 = ml[2 * mls + row * 2], l2 = ml[2 * mls + row * 2 + 1];
  float m3 = ml[3 * mls + row * 2], l3 = ml[3 * mls + row * 2 + 1];
  float M = fmaxf(fmaxf(m0, m1), fmaxf(m2, m3));
  float w0 = __expf(m0 - M), w1 = __expf(m1 - M);
  float w2 = __expf(m2 - M), w3 = __expf(m3 - M);
  float inv = 1.0f / fmaxf(w0 * l0 + w1 * l1 + w2 * l2 + w3 * l3, 1e-30f);
  float4 a = *(const float4*)(po0 + (size_t)row * 128 + c0);
  float4 b = *(const float4*)(po1 + (size_t)row * 128 + c0);
  float4 c = *(const float4*)(po2 + (size_t)row * 128 + c0);
  float4 d = *(const float4*)(po3 + (size_t)row * 128 + c0);
  int h = row / L, s = row % L;
  bf16x4 o;
  o[0] = (bf16)((w0 * a.x + w1 * b.x + w2 * c.x + w3 * d.x) * inv);
  o[1] = (bf16)((w0 * a.y + w1 * b.y + w2 * c.y + w3 * d.y) * inv);
  o[2] = (bf16)((w0 * a.z + w1 * b.z + w2 * c.z + w3 * d.z) * inv);
  o[3] = (bf16)((w0 * a.w + w1 * b.w + w2 * c.w + w3 * d.w) * inv);
  *(bf16x4*)(attn + (size_t)s * 1536 + h * 128 + c0) = o;
}

// ---------------- launcher ----------------
extern "C" void kernel_launch(void* const* d_in, const int* in_sizes, int n_in,
                              void* d_out, int out_size, void* d_ws, size_t ws_size,
                              hipStream_t stream) {
  const float* x = (const float*)d_in[0];
  const int* seq_lens = (const int*)d_in[1];
  const int* grid_sizes = (const int*)d_in[2];
  const float* freqs = (const float*)d_in[3];
  const float* Wq = (const float*)d_in[4];
  const float* bq = (const float*)d_in[5];
  const float* Wk = (const float*)d_in[6];
  const float* bk = (const float*)d_in[7];
  const float* Wv = (const float*)d_in[8];
  const float* bv = (const float*)d_in[9];
  const float* Wo = (const float*)d_in[10];
  const float* bo = (const float*)d_in[11];
  const float* gq = (const float*)d_in[12];
  const float* gk = (const float*)d_in[13];

  char* ws = (char*)d_ws;
  bf16* x_bf = (bf16*)(ws + 0);             // 11,010,048  (dead after QKV GEMM)
  bf16* wqkvt = (bf16*)(ws + 11010048);     // 14,155,776  (dead after QKV GEMM)
  bf16* wot = (bf16*)(ws + 25165824);       //  4,718,592  (live until final GEMM)
  float* bqkv = (float*)(ws + 29884416);    //     18,432
  bf16* QKV = (bf16*)(ws + 29902848);       // 33,030,144  (dead after transpose_v)
  bf16* qb = (bf16*)(ws + 62932992);        // 11,010,048
  bf16* kb = (bf16*)(ws + 73943040);        // 11,010,048
  bf16* vT = (bf16*)(ws + 84953088);        // 11,010,048
  float* tabc = (float*)(ws + 95963136);    //    917,504  (dead after postproc)
  float* tabs = (float*)(ws + 96880640);    //    917,504  (dead after postproc)
  // overlays for the flash phase (underlying buffers dead by then).
  // Footprint peaks at 141,838,336 B == the R1 layout size (already exercised).
  float* po0 = (float*)(ws + 29902848);     // 22,020,096 over QKV
  bf16* attn = (bf16*)(ws + 51922944);      // 11,010,048 over QKV tail
  float* po1 = (float*)(ws + 0);            // 22,020,096 over x_bf+wqkvt
  float* ml  = (float*)(ws + 95963136);     //  1,376,256 over tabc+tabs
  float* po2 = (float*)(ws + 97798144);     // 22,020,096 tail
  float* po3 = (float*)(ws + 119818240);    // 22,020,096 tail (ends 141,838,336)

  cast_f32_bf16<<<2688, 256, 0, stream>>>(x, x_bf, 688128);
  transpose_w<<<dim3(24, 24), 256, 0, stream>>>(Wq, wqkvt);
  transpose_w<<<dim3(24, 24), 256, 0, stream>>>(Wk, wqkvt + 1536 * 1536);
  transpose_w<<<dim3(24, 24), 256, 0, stream>>>(Wv, wqkvt + 2 * 1536 * 1536);
  transpose_w<<<dim3(24, 24), 256, 0, stream>>>(Wo, wot);
  concat_bias<<<18, 256, 0, stream>>>(bq, bk, bv, bqkv);
  rope_tab<<<896, 256, 0, stream>>>(freqs, grid_sizes, tabc, tabs);
  gemm_bt<bf16><<<dim3(28, 36), 256, 0, stream>>>(x_bf, wqkvt, bqkv, QKV, 3584, 4608, 1536);
  postproc<<<3584, 256, 0, stream>>>(QKV, gq, gk, tabc, tabs, qb, kb);
  transpose_v<<<dim3(56, 12), 256, 0, stream>>>(QKV, vT);
  flash_attn<<<dim3(28, 12, 4), 256, 0, stream>>>(qb, kb, vT, seq_lens, po0, po1, po2, po3, ml);
  combine4<<<5376, 256, 0, stream>>>(po0, po1, po2, po3, ml, attn);
  gemm_bt<float><<<dim3(28, 12), 256, 0, stream>>>(attn, wot, bo, (float*)d_out, 3584, 1536, 1536);
}

// Round 9
// 275.325 us; speedup vs baseline: 1.0894x; 1.0223x over previous
//
#include <hip/hip_runtime.h>

typedef __bf16 bf16;
typedef __bf16 bf16x8 __attribute__((ext_vector_type(8)));
typedef __bf16 bf16x4 __attribute__((ext_vector_type(4)));
typedef float f32x4 __attribute__((ext_vector_type(4)));

__device__ __forceinline__ void gload_lds16(const void* g, void* l) {
  __builtin_amdgcn_global_load_lds(
      (const __attribute__((address_space(1))) void*)g,
      (__attribute__((address_space(3))) void*)l, 16, 0, 0);
}

__device__ __forceinline__ bf16x8 ld8(const bf16* p) {
  bf16x8 v; __builtin_memcpy(&v, p, 16); return v;
}

// ---------------- cast x (fp32 -> bf16), 8 elems/thread ----------------
__global__ __launch_bounds__(256) void cast_f32_bf16(const float* __restrict__ in,
                                                     bf16* __restrict__ out, int n8) {
  int i = blockIdx.x * 256 + threadIdx.x;
  if (i >= n8) return;
  const float4* p = (const float4*)in + (size_t)i * 2;
  float4 a = p[0], b = p[1];
  bf16x8 o;
  o[0] = (bf16)a.x; o[1] = (bf16)a.y; o[2] = (bf16)a.z; o[3] = (bf16)a.w;
  o[4] = (bf16)b.x; o[5] = (bf16)b.y; o[6] = (bf16)b.z; o[7] = (bf16)b.w;
  *((bf16x8*)out + i) = o;
}

// ---------------- transpose W (fp32 [K][N]) -> Wt (bf16 [N][K]) ----------------
__global__ __launch_bounds__(256) void transpose_w(const float* __restrict__ W,
                                                   bf16* __restrict__ Wt) {
  __shared__ bf16 tile[64][72];
  int t = threadIdx.x;
  int k0 = blockIdx.x * 64, n0 = blockIdx.y * 64;
  int r = t >> 2, c0 = (t & 3) * 16;
  const float* src = W + (size_t)(k0 + r) * 1536 + n0 + c0;
#pragma unroll
  for (int q = 0; q < 4; ++q) {
    float4 v = *(const float4*)(src + q * 4);
    tile[c0 + q * 4 + 0][r] = (bf16)v.x;
    tile[c0 + q * 4 + 1][r] = (bf16)v.y;
    tile[c0 + q * 4 + 2][r] = (bf16)v.z;
    tile[c0 + q * 4 + 3][r] = (bf16)v.w;
  }
  __syncthreads();
  bf16* dst = Wt + (size_t)(n0 + r) * 1536 + k0 + c0;
  bf16x8 o0, o1;
#pragma unroll
  for (int j = 0; j < 8; ++j) { o0[j] = tile[r][c0 + j]; o1[j] = tile[r][c0 + 8 + j]; }
  *(bf16x8*)dst = o0;
  *(bf16x8*)(dst + 8) = o1;
}

__global__ void concat_bias(const float* __restrict__ bq, const float* __restrict__ bk,
                            const float* __restrict__ bv, float* __restrict__ o) {
  int t = blockIdx.x * 256 + threadIdx.x;
  if (t < 1536) o[t] = bq[t];
  else if (t < 3072) o[t] = bk[t - 1536];
  else if (t < 4608) o[t] = bv[t - 3072];
}

// ---------------- m97-structure GEMM: C[M][N] = A[M][K](bf16) * B[N][K](bf16)^T + bias ----------------
template <typename OUT>
__global__ __launch_bounds__(256, 2) void gemm_bt(const bf16* __restrict__ A, const bf16* __restrict__ B,
                                                  const float* __restrict__ bias, OUT* __restrict__ C,
                                                  int M, int N, int K) {
  __shared__ bf16 As[128 * 32], Bs[128 * 32];
  int t = threadIdx.x, l = t & 63, w = t >> 6;
  int lane15 = l & 15, lhi = l >> 4;
  int m0 = blockIdx.x * 128, n0 = blockIdx.y * 128;
  int wm = (w >> 1) * 64, wn = (w & 1) * 64;
  f32x4 zero = {0.f, 0.f, 0.f, 0.f};
  f32x4 acc[4][4];
#pragma unroll
  for (int i = 0; i < 4; ++i)
#pragma unroll
    for (int j = 0; j < 4; ++j) acc[i][j] = zero;

  int srow = t >> 2, scol = (t & 3) * 8;
  const bf16* gA0 = A + (size_t)(m0 + srow) * K + scol;
  const bf16* gA1 = A + (size_t)(m0 + 64 + srow) * K + scol;
  const bf16* gB0 = B + (size_t)(n0 + srow) * K + scol;
  const bf16* gB1 = B + (size_t)(n0 + 64 + srow) * K + scol;
  char* ldsA = (char*)As + (size_t)w * 1024;
  char* ldsB = (char*)Bs + (size_t)w * 1024;

  for (int kt = 0; kt < K; kt += 32) {
    gload_lds16(gA0 + kt, ldsA);
    gload_lds16(gA1 + kt, ldsA + 4096);
    gload_lds16(gB0 + kt, ldsB);
    gload_lds16(gB1 + kt, ldsB + 4096);
    __syncthreads();
    bf16x8 af[4], bfr[4];
#pragma unroll
    for (int i = 0; i < 4; ++i) {
      af[i]  = ld8(&As[(wm + i * 16 + lane15) * 32 + lhi * 8]);
      bfr[i] = ld8(&Bs[(wn + i * 16 + lane15) * 32 + lhi * 8]);
    }
#pragma unroll
    for (int i = 0; i < 4; ++i)
#pragma unroll
      for (int j = 0; j < 4; ++j)
        acc[i][j] = __builtin_amdgcn_mfma_f32_16x16x32_bf16(af[i], bfr[j], acc[i][j], 0, 0, 0);
    __syncthreads();
  }
#pragma unroll
  for (int i = 0; i < 4; ++i)
#pragma unroll
    for (int j = 0; j < 4; ++j) {
      int col = n0 + wn + j * 16 + lane15;
      float bb = bias[col];
#pragma unroll
      for (int r = 0; r < 4; ++r) {
        int row = m0 + wm + i * 16 + lhi * 4 + r;
        C[(size_t)row * N + col] = (OUT)(acc[i][j][r] + bb);
      }
    }
}

// ---------------- RoPE cos/sin table [3584][64] ----------------
__global__ void rope_tab(const float* __restrict__ freqs, const int* __restrict__ gs,
                         float* __restrict__ tabc, float* __restrict__ tabs) {
  int idx = blockIdx.x * 256 + threadIdx.x;
  if (idx >= 3584 * 64) return;
  int s = idx >> 6, i = idx & 63;
  int H = gs[1], W = gs[2];
  int f = s / (H * W);
  int rem = s - f * (H * W);
  int hh = rem / W;
  int ww = rem - hh * W;
  int row = (i < 22) ? f : ((i < 43) ? hh : ww);
  float a = freqs[row * 64 + i];
  tabc[idx] = cosf(a);
  tabs[idx] = sinf(a);
}

// ---------------- RMSNorm + RoPE for Q,K; write head-major bf16 ----------------
// Q is pre-scaled by 1/sqrt(128): RoPE is linear so scaling commutes, and the
// flash kernel then skips the per-score multiply.
__global__ __launch_bounds__(256) void postproc(const bf16* __restrict__ QKV,
    const float* __restrict__ gq, const float* __restrict__ gk,
    const float* __restrict__ tabc, const float* __restrict__ tabs,
    bf16* __restrict__ qb, bf16* __restrict__ kb) {
  int s = blockIdx.x, t = threadIdx.x;
  const bf16* Qr = QKV + (size_t)s * 4608;
  const bf16* Kr = Qr + 1536;
  int j0 = t * 6;
  float qv[6], kv[6];
  float sq = 0.f, sk = 0.f;
#pragma unroll
  for (int j = 0; j < 6; ++j) {
    float a = (float)Qr[j0 + j]; qv[j] = a; sq += a * a;
    float b = (float)Kr[j0 + j]; kv[j] = b; sk += b * b;
  }
#pragma unroll
  for (int off = 32; off > 0; off >>= 1) {
    sq += __shfl_down(sq, off);
    sk += __shfl_down(sk, off);
  }
  __shared__ float red[2][4];
  if ((t & 63) == 0) { red[0][t >> 6] = sq; red[1][t >> 6] = sk; }
  __syncthreads();
  float vq = (red[0][0] + red[0][1]) + (red[0][2] + red[0][3]);
  float vk = (red[1][0] + red[1][1]) + (red[1][2] + red[1][3]);
  float rq = 1.0f / sqrtf(vq * (1.0f / 1536.0f) + 1e-6f);
  float rk = 1.0f / sqrtf(vk * (1.0f / 1536.0f) + 1e-6f);
  rq *= 0.08838834764831845f;   // fold attention scale into Q
#pragma unroll
  for (int j = 0; j < 6; j += 2) {
    int jj = j0 + j;
    int d = jj & 127, i = d >> 1, h = jj >> 7;
    float c = tabc[s * 64 + i], sn = tabs[s * 64 + i];
    size_t base = (((size_t)h * 3584 + s) << 7) + d;
    float a = qv[j] * rq * gq[jj], b = qv[j + 1] * rq * gq[jj + 1];
    qb[base] = (bf16)(a * c - b * sn);
    qb[base + 1] = (bf16)(a * sn + b * c);
    float ak = kv[j] * rk * gk[jj], bk2 = kv[j + 1] * rk * gk[jj + 1];
    kb[base] = (bf16)(ak * c - bk2 * sn);
    kb[base + 1] = (bf16)(ak * sn + bk2 * c);
  }
}

// ---------------- V -> transposed bf16 vT [12][128][3584], slot-permuted ----------------
// Within each 64-kv block, kv are stored at MFMA slot positions:
// slot(kv=8*mm+j) = sA(mm) + 8*(j>>2) + (j&3),  sA = 32*(mm>>2)+16*(mm&1)+4*((mm>>1)&1).
// This makes flash's V staging a single b128 copy (same pattern as K).
__global__ __launch_bounds__(256) void transpose_v(const bf16* __restrict__ QKV,
                                                   bf16* __restrict__ vT) {
  __shared__ bf16 tile[128][72];
  int t = threadIdx.x;
  int h = blockIdx.y;
  int s0 = blockIdx.x * 64;
  int r = t >> 2, c0 = (t & 3) * 32;
  const bf16* src = QKV + (size_t)(s0 + r) * 4608 + 3072 + h * 128 + c0;
#pragma unroll
  for (int q = 0; q < 4; ++q) {
    bf16x8 v = ld8(src + q * 8);
#pragma unroll
    for (int j = 0; j < 8; ++j) tile[c0 + q * 8 + j][r] = v[j];
  }
  __syncthreads();
  int d = t >> 1, spHalf = t & 1;
  bf16* dstBase = vT + (size_t)(h * 128 + d) * 3584 + s0;
#pragma unroll
  for (int q = 0; q < 4; ++q) {
    int mm = spHalf * 4 + q;
    int sA = 32 * (mm >> 2) + 16 * (mm & 1) + 4 * ((mm >> 1) & 1);
    bf16x4 lo, hi;
#pragma unroll
    for (int j = 0; j < 4; ++j) {
      lo[j] = tile[d][spHalf * 32 + q * 8 + j];
      hi[j] = tile[d][spHalf * 32 + q * 8 + 4 + j];
    }
    *(bf16x4*)(dstBase + sA) = lo;
    *(bf16x4*)(dstBase + sA + 8) = hi;
  }
}

// ---------------- flash attention v4: single-buffer 32KB, split-4, 5 blocks/CU ----------------
// grid (28, 12, 4). Swapped mfma(K,Q): lane owns q = lane&15 (16 P values);
// slot-permuted vT makes the lane's own P values exactly its PV A-fragment.
// Single-buffered K+V (32 KB LDS -> 5 blocks/CU; supply 1344/256 = 5.25/CU).
// Two barriers/tile (RAW after stage, WAR after PV) — lockstep is covered by
// ~5 resident blocks (R7's regression was at 2.6-block supply).
// Prefetch = plain register loads issued before the barrier: s_barrier does NOT
// drain VGPR-targeted vmcnt (only global_load_lds); waitcnt lands at next stage.
// Partials in bf16 (halves combine traffic). Q pre-scaled in postproc.
// launch_bounds min-waves MUST stay 2 (R4: (256,3) spilled the accumulators).
__global__ __launch_bounds__(256, 2) void flash_attn(
    const bf16* __restrict__ qb, const bf16* __restrict__ kb, const bf16* __restrict__ vT,
    const int* __restrict__ sl, bf16* __restrict__ po0, bf16* __restrict__ po1,
    bf16* __restrict__ po2, bf16* __restrict__ po3, float* __restrict__ ml) {
  const int L = 3584;
  __shared__ bf16 Ks[64 * 128];   // [kv][d], XOR-swizzled byte ^= ((kv&7)<<4)
  __shared__ bf16 Vs[128 * 64];   // [d][slot], XOR-swizzled byte ^= ((d&7)<<4)
  int t = threadIdx.x, l = t & 63, w = t >> 6;
  int lane15 = l & 15, lhi = l >> 4;
  int grp48 = l & 48;
  int h = blockIdx.y, z = blockIdx.z;
  int qw = blockIdx.x * 128 + w * 32;
  int seqlen = sl[0];
  bf16* po = (z == 0) ? po0 : (z == 1) ? po1 : (z == 2) ? po2 : po3;
  float* mlz = ml + (size_t)z * 12 * L * 2;

  bf16x8 aq[2][4];
#pragma unroll
  for (int qf = 0; qf < 2; ++qf)
#pragma unroll
    for (int kc = 0; kc < 4; ++kc)
      aq[qf][kc] = ld8(qb + (((size_t)h * L + qw + qf * 16 + lane15) << 7) + kc * 32 + lhi * 8);

  f32x4 zero = {0.f, 0.f, 0.f, 0.f};
  f32x4 out[2][8];
  float m2[2] = {-1e30f, -1e30f}, ls2[2] = {0.f, 0.f};
#pragma unroll
  for (int qf = 0; qf < 2; ++qf)
#pragma unroll
    for (int df = 0; df < 8; ++df) out[qf][df] = zero;

  int nt = (seqlen + 63) >> 6;
  if (nt > 56) nt = 56;
  int t0 = z * 14, t1 = t0 + 14;
  if (t0 > nt) t0 = nt;
  if (t1 > nt) t1 = nt;

  // staging coordinates (constant per thread); K and V use the same pattern now
  int rk_s = t >> 4, ck_s = (t & 15) * 16;   // K: row-sub (16 rows/p), byte col in 256B row
  int rv_s = t >> 3, cv_s = (t & 7) * 16;    // V: row-sub (32 rows/p), byte col in 128B row
  int swzk = (rk_s & 7) << 4;
  int swzv = (rv_s & 7) << 4;

  bf16x8 kreg[4], vreg[4];
  if (t0 < t1) {
    int kv0 = t0 * 64;
#pragma unroll
    for (int p = 0; p < 4; ++p) {
      kreg[p] = ld8(kb + (((size_t)h * L + kv0 + p * 16 + rk_s) << 7) + (ck_s >> 1));
      vreg[p] = ld8(vT + (size_t)(h * 128 + p * 32 + rv_s) * L + kv0 + (cv_s >> 1));
    }
  }

  for (int ti = t0; ti < t1; ++ti) {
    int kv0 = ti * 64;
    // ---- stage writes (both b128, swizzled) ----
#pragma unroll
    for (int p = 0; p < 4; ++p) {
      __builtin_memcpy((char*)Ks + (p * 16 + rk_s) * 256 + (ck_s ^ swzk), &kreg[p], 16);
      __builtin_memcpy((char*)Vs + (p * 32 + rv_s) * 128 + (cv_s ^ swzv), &vreg[p], 16);
    }
    // ---- prefetch next tile (register loads; barrier does not drain these) ----
    if (ti + 1 < t1) {
      int kn = (ti + 1) * 64;
#pragma unroll
      for (int p = 0; p < 4; ++p) {
        kreg[p] = ld8(kb + (((size_t)h * L + kn + p * 16 + rk_s) << 7) + (ck_s >> 1));
        vreg[p] = ld8(vT + (size_t)(h * 128 + p * 32 + rv_s) * L + kn + (cv_s >> 1));
      }
    }
    __syncthreads();   // RAW: stages visible

    // ---- S^T = mfma(K, Q): lane owns q = lane15; kv = 16a + 4*lhi + r ----
    f32x4 sc[2][4];
#pragma unroll
    for (int qf = 0; qf < 2; ++qf)
#pragma unroll
      for (int a = 0; a < 4; ++a) sc[qf][a] = zero;
#pragma unroll
    for (int a = 0; a < 4; ++a) {
      int rk = a * 16 + lane15;
      const char* krow = (const char*)Ks + rk * 256;
      int swz = (rk & 7) << 4;
#pragma unroll
      for (int kc = 0; kc < 4; ++kc) {
        bf16x8 bk_ = ld8((const bf16*)(krow + ((kc * 64 + lhi * 16) ^ swz)));
        sc[0][a] = __builtin_amdgcn_mfma_f32_16x16x32_bf16(bk_, aq[0][kc], sc[0][a], 0, 0, 0);
        sc[1][a] = __builtin_amdgcn_mfma_f32_16x16x32_bf16(bk_, aq[1][kc], sc[1][a], 0, 0, 0);
      }
    }

    // ---- in-register online softmax (scores already scaled via Q) ----
    bool full = (kv0 + 64 <= seqlen);
    bf16x8 ap[2][2];
#pragma unroll
    for (int qf = 0; qf < 2; ++qf) {
      float tm = -1e30f;
#pragma unroll
      for (int a = 0; a < 4; ++a)
#pragma unroll
        for (int r = 0; r < 4; ++r) {
          float s = sc[qf][a][r];
          if (!full) {
            int col = kv0 + a * 16 + lhi * 4 + r;
            s = (col < seqlen) ? s : -1e30f;
            sc[qf][a][r] = s;
          }
          tm = fmaxf(tm, s);
        }
      tm = fmaxf(tm, __shfl_xor(tm, 16));
      tm = fmaxf(tm, __shfl_xor(tm, 32));
      if (!__all(tm <= m2[qf] + 8.0f)) {   // defer-max: rescale only on real growth
        float nm = fmaxf(m2[qf], tm);
        float f = __expf(m2[qf] - nm);
        m2[qf] = nm;
        ls2[qf] *= f;
#pragma unroll
        for (int r = 0; r < 4; ++r) {
          float fr = __shfl(f, grp48 | (lhi * 4 + r));   // stats live at lane&15 == q
#pragma unroll
          for (int df = 0; df < 8; ++df) out[qf][df][r] *= fr;
        }
      }
      float psum = 0.f;
#pragma unroll
      for (int a = 0; a < 4; ++a)
#pragma unroll
        for (int r = 0; r < 4; ++r) {
          float p = __expf(sc[qf][a][r] - m2[qf]);
          sc[qf][a][r] = p;
          psum += p;
        }
      psum += __shfl_xor(psum, 16);
      psum += __shfl_xor(psum, 32);
      ls2[qf] += psum;
      // PV A-fragments: own values in slot order [p[2c][0..3], p[2c+1][0..3]]
#pragma unroll
      for (int c = 0; c < 2; ++c) {
        bf16x8 f8;
#pragma unroll
        for (int r = 0; r < 4; ++r) {
          f8[r] = (bf16)sc[qf][2 * c][r];
          f8[r + 4] = (bf16)sc[qf][2 * c + 1][r];
        }
        ap[qf][c] = f8;
      }
    }

    // ---- O += P V (V read at matching slots) ----
#pragma unroll
    for (int df = 0; df < 8; ++df) {
      int rd = df * 16 + lane15;
      const char* vrow2 = (const char*)Vs + rd * 128;
      int swz = (rd & 7) << 4;
#pragma unroll
      for (int c = 0; c < 2; ++c) {
        bf16x8 bv_ = ld8((const bf16*)(vrow2 + ((c * 64 + lhi * 16) ^ swz)));
        out[0][df] = __builtin_amdgcn_mfma_f32_16x16x32_bf16(ap[0][c], bv_, out[0][df], 0, 0, 0);
        out[1][df] = __builtin_amdgcn_mfma_f32_16x16x32_bf16(ap[1][c], bv_, out[1][df], 0, 0, 0);
      }
    }
    __syncthreads();   // WAR: all waves done reading before next stage overwrite
  }

  // ---- write unnormalized partials (bf16) + (m, l) ----
#pragma unroll
  for (int qf = 0; qf < 2; ++qf) {
#pragma unroll
    for (int r = 0; r < 4; ++r) {
      int row = qw + qf * 16 + lhi * 4 + r;
      size_t rbase = ((size_t)h * L + row) << 7;
#pragma unroll
      for (int df = 0; df < 8; ++df)
        po[rbase + df * 16 + lane15] = (bf16)out[qf][df][r];
    }
    if (lhi == 0) {
      int row = qw + qf * 16 + lane15;
      mlz[(((size_t)h * L + row) << 1)] = m2[qf];
      mlz[(((size_t)h * L + row) << 1) + 1] = ls2[qf];
    }
  }
}

// ---------------- combine the four KV-split slices (bf16 partials) ----------------
__global__ __launch_bounds__(256) void combine4(
    const bf16* __restrict__ po0, const bf16* __restrict__ po1,
    const bf16* __restrict__ po2, const bf16* __restrict__ po3,
    const float* __restrict__ ml, bf16* __restrict__ attn) {
  const int L = 3584;
  int row = blockIdx.x * 8 + (threadIdx.x >> 5);   // h*L + s
  int c0 = (threadIdx.x & 31) * 4;
  const size_t mls = (size_t)12 * L * 2;
  float m0 = ml[row * 2],           l0 = ml[row * 2 + 1];
  float m1 = ml[mls + row * 2],     l1 = ml[mls + row * 2 + 1];
  float m2 = ml[2 * mls + row * 2], l2 = ml[2 * mls + row * 2 + 1];
  float m3 = ml[3 * mls + row * 2], l3 = ml[3 * mls + row * 2 + 1];
  float M = fmaxf(fmaxf(m0, m1), fmaxf(m2, m3));
  float w0 = __expf(m0 - M), w1 = __expf(m1 - M);
  float w2 = __expf(m2 - M), w3 = __expf(m3 - M);
  float inv = 1.0f / fmaxf(w0 * l0 + w1 * l1 + w2 * l2 + w3 * l3, 1e-30f);
  bf16x4 a, b, c, d;
  __builtin_memcpy(&a, po0 + (size_t)row * 128 + c0, 8);
  __builtin_memcpy(&b, po1 + (size_t)row * 128 + c0, 8);
  __builtin_memcpy(&c, po2 + (size_t)row * 128 + c0, 8);
  __builtin_memcpy(&d, po3 + (size_t)row * 128 + c0, 8);
  int h = row / L, s = row % L;
  bf16x4 o;
#pragma unroll
  for (int j = 0; j < 4; ++j)
    o[j] = (bf16)((w0 * (float)a[j] + w1 * (float)b[j] + w2 * (float)c[j] + w3 * (float)d[j]) * inv);
  *(bf16x4*)(attn + (size_t)s * 1536 + h * 128 + c0) = o;
}

// ---------------- launcher ----------------
extern "C" void kernel_launch(void* const* d_in, const int* in_sizes, int n_in,
                              void* d_out, int out_size, void* d_ws, size_t ws_size,
                              hipStream_t stream) {
  const float* x = (const float*)d_in[0];
  const int* seq_lens = (const int*)d_in[1];
  const int* grid_sizes = (const int*)d_in[2];
  const float* freqs = (const float*)d_in[3];
  const float* Wq = (const float*)d_in[4];
  const float* bq = (const float*)d_in[5];
  const float* Wk = (const float*)d_in[6];
  const float* bk = (const float*)d_in[7];
  const float* Wv = (const float*)d_in[8];
  const float* bv = (const float*)d_in[9];
  const float* Wo = (const float*)d_in[10];
  const float* bo = (const float*)d_in[11];
  const float* gq = (const float*)d_in[12];
  const float* gk = (const float*)d_in[13];

  char* ws = (char*)d_ws;
  bf16* x_bf = (bf16*)(ws + 0);             // 11,010,048  (dead after QKV GEMM)
  bf16* wqkvt = (bf16*)(ws + 11010048);     // 14,155,776  (dead after QKV GEMM)
  bf16* wot = (bf16*)(ws + 25165824);       //  4,718,592  (live until final GEMM)
  float* bqkv = (float*)(ws + 29884416);    //     18,432
  bf16* QKV = (bf16*)(ws + 29902848);       // 33,030,144  (dead after transpose_v)
  bf16* qb = (bf16*)(ws + 62932992);        // 11,010,048
  bf16* kb = (bf16*)(ws + 73943040);        // 11,010,048
  bf16* vT = (bf16*)(ws + 84953088);        // 11,010,048
  float* tabc = (float*)(ws + 95963136);    //    917,504  (dead after postproc)
  float* tabs = (float*)(ws + 96880640);    //    917,504  (dead after postproc)
  // overlays for the flash phase (underlying buffers dead by then); bf16 partials
  bf16* po0 = (bf16*)(ws + 29902848);       // 11,010,048 over QKV head
  bf16* attn = (bf16*)(ws + 51922944);      // 11,010,048 over QKV tail
  bf16* po1 = (bf16*)(ws + 0);              // 11,010,048 over x_bf
  bf16* po2 = (bf16*)(ws + 11010048);       // 11,010,048 over wqkvt
  float* ml  = (float*)(ws + 95963136);     //  1,376,256 over tabc+tabs
  bf16* po3 = (bf16*)(ws + 97798144);       // 11,010,048 tail (ends 108,808,192)

  cast_f32_bf16<<<2688, 256, 0, stream>>>(x, x_bf, 688128);
  transpose_w<<<dim3(24, 24), 256, 0, stream>>>(Wq, wqkvt);
  transpose_w<<<dim3(24, 24), 256, 0, stream>>>(Wk, wqkvt + 1536 * 1536);
  transpose_w<<<dim3(24, 24), 256, 0, stream>>>(Wv, wqkvt + 2 * 1536 * 1536);
  transpose_w<<<dim3(24, 24), 256, 0, stream>>>(Wo, wot);
  concat_bias<<<18, 256, 0, stream>>>(bq, bk, bv, bqkv);
  rope_tab<<<896, 256, 0, stream>>>(freqs, grid_sizes, tabc, tabs);
  gemm_bt<bf16><<<dim3(28, 36), 256, 0, stream>>>(x_bf, wqkvt, bqkv, QKV, 3584, 4608, 1536);
  postproc<<<3584, 256, 0, stream>>>(QKV, gq, gk, tabc, tabs, qb, kb);
  transpose_v<<<dim3(56, 12), 256, 0, stream>>>(QKV, vT);
  flash_attn<<<dim3(28, 12, 4), 256, 0, stream>>>(qb, kb, vT, seq_lens, po0, po1, po2, po3, ml);
  combine4<<<5376, 256, 0, stream>>>(po0, po1, po2, po3, ml, attn);
  gemm_bt<float><<<dim3(28, 12), 256, 0, stream>>>(attn, wot, bo, (float*)d_out, 3584, 1536, 1536);
}

// Round 10
// 274.368 us; speedup vs baseline: 1.0932x; 1.0035x over previous
//
#include <hip/hip_runtime.h>

typedef __bf16 bf16;
typedef __bf16 bf16x8 __attribute__((ext_vector_type(8)));
typedef __bf16 bf16x4 __attribute__((ext_vector_type(4)));
typedef float f32x4 __attribute__((ext_vector_type(4)));

__device__ __forceinline__ void gload_lds16(const void* g, void* l) {
  __builtin_amdgcn_global_load_lds(
      (const __attribute__((address_space(1))) void*)g,
      (__attribute__((address_space(3))) void*)l, 16, 0, 0);
}

__device__ __forceinline__ bf16x8 ld8(const bf16* p) {
  bf16x8 v; __builtin_memcpy(&v, p, 16); return v;
}

// ---------------- cast x (fp32 -> bf16), 8 elems/thread ----------------
__global__ __launch_bounds__(256) void cast_f32_bf16(const float* __restrict__ in,
                                                     bf16* __restrict__ out, int n8) {
  int i = blockIdx.x * 256 + threadIdx.x;
  if (i >= n8) return;
  const float4* p = (const float4*)in + (size_t)i * 2;
  float4 a = p[0], b = p[1];
  bf16x8 o;
  o[0] = (bf16)a.x; o[1] = (bf16)a.y; o[2] = (bf16)a.z; o[3] = (bf16)a.w;
  o[4] = (bf16)b.x; o[5] = (bf16)b.y; o[6] = (bf16)b.z; o[7] = (bf16)b.w;
  *((bf16x8*)out + i) = o;
}

// ---------------- transpose W (fp32 [K][N]) -> Wt (bf16 [N][K]) ----------------
__global__ __launch_bounds__(256) void transpose_w(const float* __restrict__ W,
                                                   bf16* __restrict__ Wt) {
  __shared__ bf16 tile[64][72];
  int t = threadIdx.x;
  int k0 = blockIdx.x * 64, n0 = blockIdx.y * 64;
  int r = t >> 2, c0 = (t & 3) * 16;
  const float* src = W + (size_t)(k0 + r) * 1536 + n0 + c0;
#pragma unroll
  for (int q = 0; q < 4; ++q) {
    float4 v = *(const float4*)(src + q * 4);
    tile[c0 + q * 4 + 0][r] = (bf16)v.x;
    tile[c0 + q * 4 + 1][r] = (bf16)v.y;
    tile[c0 + q * 4 + 2][r] = (bf16)v.z;
    tile[c0 + q * 4 + 3][r] = (bf16)v.w;
  }
  __syncthreads();
  bf16* dst = Wt + (size_t)(n0 + r) * 1536 + k0 + c0;
  bf16x8 o0, o1;
#pragma unroll
  for (int j = 0; j < 8; ++j) { o0[j] = tile[r][c0 + j]; o1[j] = tile[r][c0 + 8 + j]; }
  *(bf16x8*)dst = o0;
  *(bf16x8*)(dst + 8) = o1;
}

__global__ void concat_bias(const float* __restrict__ bq, const float* __restrict__ bk,
                            const float* __restrict__ bv, float* __restrict__ o) {
  int t = blockIdx.x * 256 + threadIdx.x;
  if (t < 1536) o[t] = bq[t];
  else if (t < 3072) o[t] = bk[t - 1536];
  else if (t < 4608) o[t] = bv[t - 3072];
}

// ---------------- m97-structure GEMM: C[M][N] = A[M][K](bf16) * B[N][K](bf16)^T + bias ----------------
template <typename OUT>
__global__ __launch_bounds__(256, 2) void gemm_bt(const bf16* __restrict__ A, const bf16* __restrict__ B,
                                                  const float* __restrict__ bias, OUT* __restrict__ C,
                                                  int M, int N, int K) {
  __shared__ bf16 As[128 * 32], Bs[128 * 32];
  int t = threadIdx.x, l = t & 63, w = t >> 6;
  int lane15 = l & 15, lhi = l >> 4;
  int m0 = blockIdx.x * 128, n0 = blockIdx.y * 128;
  int wm = (w >> 1) * 64, wn = (w & 1) * 64;
  f32x4 zero = {0.f, 0.f, 0.f, 0.f};
  f32x4 acc[4][4];
#pragma unroll
  for (int i = 0; i < 4; ++i)
#pragma unroll
    for (int j = 0; j < 4; ++j) acc[i][j] = zero;

  int srow = t >> 2, scol = (t & 3) * 8;
  const bf16* gA0 = A + (size_t)(m0 + srow) * K + scol;
  const bf16* gA1 = A + (size_t)(m0 + 64 + srow) * K + scol;
  const bf16* gB0 = B + (size_t)(n0 + srow) * K + scol;
  const bf16* gB1 = B + (size_t)(n0 + 64 + srow) * K + scol;
  char* ldsA = (char*)As + (size_t)w * 1024;
  char* ldsB = (char*)Bs + (size_t)w * 1024;

  for (int kt = 0; kt < K; kt += 32) {
    gload_lds16(gA0 + kt, ldsA);
    gload_lds16(gA1 + kt, ldsA + 4096);
    gload_lds16(gB0 + kt, ldsB);
    gload_lds16(gB1 + kt, ldsB + 4096);
    __syncthreads();
    bf16x8 af[4], bfr[4];
#pragma unroll
    for (int i = 0; i < 4; ++i) {
      af[i]  = ld8(&As[(wm + i * 16 + lane15) * 32 + lhi * 8]);
      bfr[i] = ld8(&Bs[(wn + i * 16 + lane15) * 32 + lhi * 8]);
    }
#pragma unroll
    for (int i = 0; i < 4; ++i)
#pragma unroll
      for (int j = 0; j < 4; ++j)
        acc[i][j] = __builtin_amdgcn_mfma_f32_16x16x32_bf16(af[i], bfr[j], acc[i][j], 0, 0, 0);
    __syncthreads();
  }
#pragma unroll
  for (int i = 0; i < 4; ++i)
#pragma unroll
    for (int j = 0; j < 4; ++j) {
      int col = n0 + wn + j * 16 + lane15;
      float bb = bias[col];
#pragma unroll
      for (int r = 0; r < 4; ++r) {
        int row = m0 + wm + i * 16 + lhi * 4 + r;
        C[(size_t)row * N + col] = (OUT)(acc[i][j][r] + bb);
      }
    }
}

// ---------------- RoPE cos/sin table [3584][64] ----------------
__global__ void rope_tab(const float* __restrict__ freqs, const int* __restrict__ gs,
                         float* __restrict__ tabc, float* __restrict__ tabs) {
  int idx = blockIdx.x * 256 + threadIdx.x;
  if (idx >= 3584 * 64) return;
  int s = idx >> 6, i = idx & 63;
  int H = gs[1], W = gs[2];
  int f = s / (H * W);
  int rem = s - f * (H * W);
  int hh = rem / W;
  int ww = rem - hh * W;
  int row = (i < 22) ? f : ((i < 43) ? hh : ww);
  float a = freqs[row * 64 + i];
  tabc[idx] = cosf(a);
  tabs[idx] = sinf(a);
}

// ---------------- RMSNorm + RoPE for Q,K; write head-major bf16 ----------------
// Q is pre-scaled by 1/sqrt(128): RoPE is linear so scaling commutes, and the
// flash kernel then skips the per-score multiply.
__global__ __launch_bounds__(256) void postproc(const bf16* __restrict__ QKV,
    const float* __restrict__ gq, const float* __restrict__ gk,
    const float* __restrict__ tabc, const float* __restrict__ tabs,
    bf16* __restrict__ qb, bf16* __restrict__ kb) {
  int s = blockIdx.x, t = threadIdx.x;
  const bf16* Qr = QKV + (size_t)s * 4608;
  const bf16* Kr = Qr + 1536;
  int j0 = t * 6;
  float qv[6], kv[6];
  float sq = 0.f, sk = 0.f;
#pragma unroll
  for (int j = 0; j < 6; ++j) {
    float a = (float)Qr[j0 + j]; qv[j] = a; sq += a * a;
    float b = (float)Kr[j0 + j]; kv[j] = b; sk += b * b;
  }
#pragma unroll
  for (int off = 32; off > 0; off >>= 1) {
    sq += __shfl_down(sq, off);
    sk += __shfl_down(sk, off);
  }
  __shared__ float red[2][4];
  if ((t & 63) == 0) { red[0][t >> 6] = sq; red[1][t >> 6] = sk; }
  __syncthreads();
  float vq = (red[0][0] + red[0][1]) + (red[0][2] + red[0][3]);
  float vk = (red[1][0] + red[1][1]) + (red[1][2] + red[1][3]);
  float rq = 1.0f / sqrtf(vq * (1.0f / 1536.0f) + 1e-6f);
  float rk = 1.0f / sqrtf(vk * (1.0f / 1536.0f) + 1e-6f);
  rq *= 0.08838834764831845f;   // fold attention scale into Q
#pragma unroll
  for (int j = 0; j < 6; j += 2) {
    int jj = j0 + j;
    int d = jj & 127, i = d >> 1, h = jj >> 7;
    float c = tabc[s * 64 + i], sn = tabs[s * 64 + i];
    size_t base = (((size_t)h * 3584 + s) << 7) + d;
    float a = qv[j] * rq * gq[jj], b = qv[j + 1] * rq * gq[jj + 1];
    qb[base] = (bf16)(a * c - b * sn);
    qb[base + 1] = (bf16)(a * sn + b * c);
    float ak = kv[j] * rk * gk[jj], bk2 = kv[j + 1] * rk * gk[jj + 1];
    kb[base] = (bf16)(ak * c - bk2 * sn);
    kb[base + 1] = (bf16)(ak * sn + bk2 * c);
  }
}

// ---------------- V -> transposed bf16 vT [12][128][3584], slot-permuted ----------------
__global__ __launch_bounds__(256) void transpose_v(const bf16* __restrict__ QKV,
                                                   bf16* __restrict__ vT) {
  __shared__ bf16 tile[128][72];
  int t = threadIdx.x;
  int h = blockIdx.y;
  int s0 = blockIdx.x * 64;
  int r = t >> 2, c0 = (t & 3) * 32;
  const bf16* src = QKV + (size_t)(s0 + r) * 4608 + 3072 + h * 128 + c0;
#pragma unroll
  for (int q = 0; q < 4; ++q) {
    bf16x8 v = ld8(src + q * 8);
#pragma unroll
    for (int j = 0; j < 8; ++j) tile[c0 + q * 8 + j][r] = v[j];
  }
  __syncthreads();
  int d = t >> 1, spHalf = t & 1;
  bf16* dstBase = vT + (size_t)(h * 128 + d) * 3584 + s0;
#pragma unroll
  for (int q = 0; q < 4; ++q) {
    int mm = spHalf * 4 + q;
    int sA = 32 * (mm >> 2) + 16 * (mm & 1) + 4 * ((mm >> 1) & 1);
    bf16x4 lo, hi;
#pragma unroll
    for (int j = 0; j < 4; ++j) {
      lo[j] = tile[d][spHalf * 32 + q * 8 + j];
      hi[j] = tile[d][spHalf * 32 + q * 8 + 4 + j];
    }
    *(bf16x4*)(dstBase + sA) = lo;
    *(bf16x4*)(dstBase + sA + 8) = hi;
  }
}

// ---------------- flash attention v5: XCD-locality remap ----------------
// 1-D grid of 1344 blocks. Dispatcher maps wg i -> XCD i%8 (m09/m157 model),
// so we place all 28 q-blocks of a (h,z) pair at slots == (pair%8) mod 8:
//   b = xcd + 8*(pg*28 + x),  pair p = pg*8 + xcd,  h = p%12, z = p/12.
// Per-XCD K/V working set: 6 pairs x 0.46 MB = 2.8 MB < 4 MB L2 (was ~22 MB
// scattered -> thrash -> ~900cy HBM-latency stalls; R6-R9 flat at ~133 us).
// Rest identical to R9 (single-buffer 32KB, split-4, in-register softmax).
// launch_bounds min-waves MUST stay 2 (R4: (256,3) spilled the accumulators).
__global__ __launch_bounds__(256, 2) void flash_attn(
    const bf16* __restrict__ qb, const bf16* __restrict__ kb, const bf16* __restrict__ vT,
    const int* __restrict__ sl, bf16* __restrict__ po0, bf16* __restrict__ po1,
    bf16* __restrict__ po2, bf16* __restrict__ po3, float* __restrict__ ml) {
  const int L = 3584;
  __shared__ bf16 Ks[64 * 128];   // [kv][d], XOR-swizzled byte ^= ((kv&7)<<4)
  __shared__ bf16 Vs[128 * 64];   // [d][slot], XOR-swizzled byte ^= ((d&7)<<4)
  int t = threadIdx.x, l = t & 63, w = t >> 6;
  int lane15 = l & 15, lhi = l >> 4;
  int grp48 = l & 48;
  // XCD-locality decode
  int b = blockIdx.x;
  int xcd = b & 7, k_ = b >> 3;
  int pg = k_ / 28, x = k_ - pg * 28;
  int p = pg * 8 + xcd;
  int h = p % 12, z = p / 12;
  int qw = x * 128 + w * 32;
  int seqlen = sl[0];
  bf16* po = (z == 0) ? po0 : (z == 1) ? po1 : (z == 2) ? po2 : po3;
  float* mlz = ml + (size_t)z * 12 * L * 2;

  bf16x8 aq[2][4];
#pragma unroll
  for (int qf = 0; qf < 2; ++qf)
#pragma unroll
    for (int kc = 0; kc < 4; ++kc)
      aq[qf][kc] = ld8(qb + (((size_t)h * L + qw + qf * 16 + lane15) << 7) + kc * 32 + lhi * 8);

  f32x4 zero = {0.f, 0.f, 0.f, 0.f};
  f32x4 out[2][8];
  float m2[2] = {-1e30f, -1e30f}, ls2[2] = {0.f, 0.f};
#pragma unroll
  for (int qf = 0; qf < 2; ++qf)
#pragma unroll
    for (int df = 0; df < 8; ++df) out[qf][df] = zero;

  int nt = (seqlen + 63) >> 6;
  if (nt > 56) nt = 56;
  int t0 = z * 14, t1 = t0 + 14;
  if (t0 > nt) t0 = nt;
  if (t1 > nt) t1 = nt;

  // staging coordinates (constant per thread); K and V use the same pattern
  int rk_s = t >> 4, ck_s = (t & 15) * 16;   // K: row-sub, byte col in 256B row
  int rv_s = t >> 3, cv_s = (t & 7) * 16;    // V: row-sub, byte col in 128B row
  int swzk = (rk_s & 7) << 4;
  int swzv = (rv_s & 7) << 4;

  bf16x8 kreg[4], vreg[4];
  if (t0 < t1) {
    int kv0 = t0 * 64;
#pragma unroll
    for (int pp = 0; pp < 4; ++pp) {
      kreg[pp] = ld8(kb + (((size_t)h * L + kv0 + pp * 16 + rk_s) << 7) + (ck_s >> 1));
      vreg[pp] = ld8(vT + (size_t)(h * 128 + pp * 32 + rv_s) * L + kv0 + (cv_s >> 1));
    }
  }

  for (int ti = t0; ti < t1; ++ti) {
    int kv0 = ti * 64;
    // ---- stage writes (both b128, swizzled) ----
#pragma unroll
    for (int pp = 0; pp < 4; ++pp) {
      __builtin_memcpy((char*)Ks + (pp * 16 + rk_s) * 256 + (ck_s ^ swzk), &kreg[pp], 16);
      __builtin_memcpy((char*)Vs + (pp * 32 + rv_s) * 128 + (cv_s ^ swzv), &vreg[pp], 16);
    }
    // ---- prefetch next tile (register loads; barrier does not drain these) ----
    if (ti + 1 < t1) {
      int kn = (ti + 1) * 64;
#pragma unroll
      for (int pp = 0; pp < 4; ++pp) {
        kreg[pp] = ld8(kb + (((size_t)h * L + kn + pp * 16 + rk_s) << 7) + (ck_s >> 1));
        vreg[pp] = ld8(vT + (size_t)(h * 128 + pp * 32 + rv_s) * L + kn + (cv_s >> 1));
      }
    }
    __syncthreads();   // RAW: stages visible

    // ---- S^T = mfma(K, Q): lane owns q = lane15; kv = 16a + 4*lhi + r ----
    f32x4 sc[2][4];
#pragma unroll
    for (int qf = 0; qf < 2; ++qf)
#pragma unroll
      for (int a = 0; a < 4; ++a) sc[qf][a] = zero;
#pragma unroll
    for (int a = 0; a < 4; ++a) {
      int rk = a * 16 + lane15;
      const char* krow = (const char*)Ks + rk * 256;
      int swz = (rk & 7) << 4;
#pragma unroll
      for (int kc = 0; kc < 4; ++kc) {
        bf16x8 bk_ = ld8((const bf16*)(krow + ((kc * 64 + lhi * 16) ^ swz)));
        sc[0][a] = __builtin_amdgcn_mfma_f32_16x16x32_bf16(bk_, aq[0][kc], sc[0][a], 0, 0, 0);
        sc[1][a] = __builtin_amdgcn_mfma_f32_16x16x32_bf16(bk_, aq[1][kc], sc[1][a], 0, 0, 0);
      }
    }

    // ---- in-register online softmax (scores already scaled via Q) ----
    bool full = (kv0 + 64 <= seqlen);
    bf16x8 ap[2][2];
#pragma unroll
    for (int qf = 0; qf < 2; ++qf) {
      float tm = -1e30f;
#pragma unroll
      for (int a = 0; a < 4; ++a)
#pragma unroll
        for (int r = 0; r < 4; ++r) {
          float s = sc[qf][a][r];
          if (!full) {
            int col = kv0 + a * 16 + lhi * 4 + r;
            s = (col < seqlen) ? s : -1e30f;
            sc[qf][a][r] = s;
          }
          tm = fmaxf(tm, s);
        }
      tm = fmaxf(tm, __shfl_xor(tm, 16));
      tm = fmaxf(tm, __shfl_xor(tm, 32));
      if (!__all(tm <= m2[qf] + 8.0f)) {   // defer-max: rescale only on real growth
        float nm = fmaxf(m2[qf], tm);
        float f = __expf(m2[qf] - nm);
        m2[qf] = nm;
        ls2[qf] *= f;
#pragma unroll
        for (int r = 0; r < 4; ++r) {
          float fr = __shfl(f, grp48 | (lhi * 4 + r));   // stats live at lane&15 == q
#pragma unroll
          for (int df = 0; df < 8; ++df) out[qf][df][r] *= fr;
        }
      }
      float psum = 0.f;
#pragma unroll
      for (int a = 0; a < 4; ++a)
#pragma unroll
        for (int r = 0; r < 4; ++r) {
          float pv = __expf(sc[qf][a][r] - m2[qf]);
          sc[qf][a][r] = pv;
          psum += pv;
        }
      psum += __shfl_xor(psum, 16);
      psum += __shfl_xor(psum, 32);
      ls2[qf] += psum;
      // PV A-fragments: own values in slot order [p[2c][0..3], p[2c+1][0..3]]
#pragma unroll
      for (int c = 0; c < 2; ++c) {
        bf16x8 f8;
#pragma unroll
        for (int r = 0; r < 4; ++r) {
          f8[r] = (bf16)sc[qf][2 * c][r];
          f8[r + 4] = (bf16)sc[qf][2 * c + 1][r];
        }
        ap[qf][c] = f8;
      }
    }

    // ---- O += P V (V read at matching slots) ----
#pragma unroll
    for (int df = 0; df < 8; ++df) {
      int rd = df * 16 + lane15;
      const char* vrow2 = (const char*)Vs + rd * 128;
      int swz = (rd & 7) << 4;
#pragma unroll
      for (int c = 0; c < 2; ++c) {
        bf16x8 bv_ = ld8((const bf16*)(vrow2 + ((c * 64 + lhi * 16) ^ swz)));
        out[0][df] = __builtin_amdgcn_mfma_f32_16x16x32_bf16(ap[0][c], bv_, out[0][df], 0, 0, 0);
        out[1][df] = __builtin_amdgcn_mfma_f32_16x16x32_bf16(ap[1][c], bv_, out[1][df], 0, 0, 0);
      }
    }
    __syncthreads();   // WAR: all waves done reading before next stage overwrite
  }

  // ---- write unnormalized partials (bf16) + (m, l) ----
#pragma unroll
  for (int qf = 0; qf < 2; ++qf) {
#pragma unroll
    for (int r = 0; r < 4; ++r) {
      int row = qw + qf * 16 + lhi * 4 + r;
      size_t rbase = ((size_t)h * L + row) << 7;
#pragma unroll
      for (int df = 0; df < 8; ++df)
        po[rbase + df * 16 + lane15] = (bf16)out[qf][df][r];
    }
    if (lhi == 0) {
      int row = qw + qf * 16 + lane15;
      mlz[(((size_t)h * L + row) << 1)] = m2[qf];
      mlz[(((size_t)h * L + row) << 1) + 1] = ls2[qf];
    }
  }
}

// ---------------- combine the four KV-split slices (bf16 partials) ----------------
__global__ __launch_bounds__(256) void combine4(
    const bf16* __restrict__ po0, const bf16* __restrict__ po1,
    const bf16* __restrict__ po2, const bf16* __restrict__ po3,
    const float* __restrict__ ml, bf16* __restrict__ attn) {
  const int L = 3584;
  int row = blockIdx.x * 8 + (threadIdx.x >> 5);   // h*L + s
  int c0 = (threadIdx.x & 31) * 4;
  const size_t mls = (size_t)12 * L * 2;
  float m0 = ml[row * 2],           l0 = ml[row * 2 + 1];
  float m1 = ml[mls + row * 2],     l1 = ml[mls + row * 2 + 1];
  float m2 = ml[2 * mls + row * 2], l2 = ml[2 * mls + row * 2 + 1];
  float m3 = ml[3 * mls + row * 2], l3 = ml[3 * mls + row * 2 + 1];
  float M = fmaxf(fmaxf(m0, m1), fmaxf(m2, m3));
  float w0 = __expf(m0 - M), w1 = __expf(m1 - M);
  float w2 = __expf(m2 - M), w3 = __expf(m3 - M);
  float inv = 1.0f / fmaxf(w0 * l0 + w1 * l1 + w2 * l2 + w3 * l3, 1e-30f);
  bf16x4 a, b, c, d;
  __builtin_memcpy(&a, po0 + (size_t)row * 128 + c0, 8);
  __builtin_memcpy(&b, po1 + (size_t)row * 128 + c0, 8);
  __builtin_memcpy(&c, po2 + (size_t)row * 128 + c0, 8);
  __builtin_memcpy(&d, po3 + (size_t)row * 128 + c0, 8);
  int h = row / L, s = row % L;
  bf16x4 o;
#pragma unroll
  for (int j = 0; j < 4; ++j)
    o[j] = (bf16)((w0 * (float)a[j] + w1 * (float)b[j] + w2 * (float)c[j] + w3 * (float)d[j]) * inv);
  *(bf16x4*)(attn + (size_t)s * 1536 + h * 128 + c0) = o;
}

// ---------------- launcher ----------------
extern "C" void kernel_launch(void* const* d_in, const int* in_sizes, int n_in,
                              void* d_out, int out_size, void* d_ws, size_t ws_size,
                              hipStream_t stream) {
  const float* x = (const float*)d_in[0];
  const int* seq_lens = (const int*)d_in[1];
  const int* grid_sizes = (const int*)d_in[2];
  const float* freqs = (const float*)d_in[3];
  const float* Wq = (const float*)d_in[4];
  const float* bq = (const float*)d_in[5];
  const float* Wk = (const float*)d_in[6];
  const float* bk = (const float*)d_in[7];
  const float* Wv = (const float*)d_in[8];
  const float* bv = (const float*)d_in[9];
  const float* Wo = (const float*)d_in[10];
  const float* bo = (const float*)d_in[11];
  const float* gq = (const float*)d_in[12];
  const float* gk = (const float*)d_in[13];

  char* ws = (char*)d_ws;
  bf16* x_bf = (bf16*)(ws + 0);             // 11,010,048  (dead after QKV GEMM)
  bf16* wqkvt = (bf16*)(ws + 11010048);     // 14,155,776  (dead after QKV GEMM)
  bf16* wot = (bf16*)(ws + 25165824);       //  4,718,592  (live until final GEMM)
  float* bqkv = (float*)(ws + 29884416);    //     18,432
  bf16* QKV = (bf16*)(ws + 29902848);       // 33,030,144  (dead after transpose_v)
  bf16* qb = (bf16*)(ws + 62932992);        // 11,010,048
  bf16* kb = (bf16*)(ws + 73943040);        // 11,010,048
  bf16* vT = (bf16*)(ws + 84953088);        // 11,010,048
  float* tabc = (float*)(ws + 95963136);    //    917,504  (dead after postproc)
  float* tabs = (float*)(ws + 96880640);    //    917,504  (dead after postproc)
  // overlays for the flash phase (underlying buffers dead by then); bf16 partials
  bf16* po0 = (bf16*)(ws + 29902848);       // 11,010,048 over QKV head
  bf16* attn = (bf16*)(ws + 51922944);      // 11,010,048 over QKV tail
  bf16* po1 = (bf16*)(ws + 0);              // 11,010,048 over x_bf
  bf16* po2 = (bf16*)(ws + 11010048);       // 11,010,048 over wqkvt
  float* ml  = (float*)(ws + 95963136);     //  1,376,256 over tabc+tabs
  bf16* po3 = (bf16*)(ws + 97798144);       // 11,010,048 tail (ends 108,808,192)

  cast_f32_bf16<<<2688, 256, 0, stream>>>(x, x_bf, 688128);
  transpose_w<<<dim3(24, 24), 256, 0, stream>>>(Wq, wqkvt);
  transpose_w<<<dim3(24, 24), 256, 0, stream>>>(Wk, wqkvt + 1536 * 1536);
  transpose_w<<<dim3(24, 24), 256, 0, stream>>>(Wv, wqkvt + 2 * 1536 * 1536);
  transpose_w<<<dim3(24, 24), 256, 0, stream>>>(Wo, wot);
  concat_bias<<<18, 256, 0, stream>>>(bq, bk, bv, bqkv);
  rope_tab<<<896, 256, 0, stream>>>(freqs, grid_sizes, tabc, tabs);
  gemm_bt<bf16><<<dim3(28, 36), 256, 0, stream>>>(x_bf, wqkvt, bqkv, QKV, 3584, 4608, 1536);
  postproc<<<3584, 256, 0, stream>>>(QKV, gq, gk, tabc, tabs, qb, kb);
  transpose_v<<<dim3(56, 12), 256, 0, stream>>>(QKV, vT);
  flash_attn<<<1344, 256, 0, stream>>>(qb, kb, vT, seq_lens, po0, po1, po2, po3, ml);
  combine4<<<5376, 256, 0, stream>>>(po0, po1, po2, po3, ml, attn);
  gemm_bt<float><<<dim3(28, 12), 256, 0, stream>>>(attn, wot, bo, (float*)d_out, 3584, 1536, 1536);
}